// Round 15
// baseline (587.752 us; speedup 1.0000x reference)
//
#include <hip/hip_runtime.h>
#include <hip/hip_bf16.h>
#include <stdint.h>

// Problem constants
#define BB   2
#define SS   2048
#define HHH  2048
#define NHH  16
#define HDD  128
#define MTOT 4096   // BB*SS

typedef __bf16 bf16x8 __attribute__((ext_vector_type(8)));
typedef float  f32x4  __attribute__((ext_vector_type(4)));
typedef float  f32x16 __attribute__((ext_vector_type(16)));

#define MFMA16(a, b, c) __builtin_amdgcn_mfma_f32_16x16x32_bf16((a), (b), (c), 0, 0, 0)
#define MFMA32(a, b, c) __builtin_amdgcn_mfma_f32_32x32x16_bf16((a), (b), (c), 0, 0, 0)

__device__ __forceinline__ unsigned short f2bf(float f) {
    union { float f; unsigned u; } v; v.f = f;
    unsigned r = v.u + 0x7FFFu + ((v.u >> 16) & 1u);   // RNE
    return (unsigned short)(r >> 16);
}

__device__ __forceinline__ unsigned packbf(float a, float b) {
    union { __bf16 h[2]; unsigned u; } p;
    p.h[0] = (__bf16)a; p.h[1] = (__bf16)b;
    return p.u;
}

// v_permlane32_swap_b32: a' = [a.lo32, b.lo32], b' = [a.hi32, b.hi32]
__device__ __forceinline__ void pswap(unsigned &a, unsigned &b) {
    asm("v_permlane32_swap_b32 %0, %1" : "+v"(a), "+v"(b));
}

// cross-half (lane ^ 32) pair: returns {own-half view, other-half view}
__device__ __forceinline__ float2 xswap(float x) {
    unsigned a = __builtin_bit_cast(unsigned, x);
    unsigned b;
    asm("v_mov_b32 %0, %1" : "=v"(b) : "v"(a));   // force distinct register
    asm("v_permlane32_swap_b32 %0, %1" : "+v"(a), "+v"(b));
    return make_float2(__builtin_bit_cast(float, a), __builtin_bit_cast(float, b));
}

// async global->LDS, 16B per lane. LDS dest is wave-uniform base + lane*16.
__device__ __forceinline__ void gload16(const void* src, void* lds) {
    __builtin_amdgcn_global_load_lds(
        (__attribute__((address_space(1))) void*)src,
        (__attribute__((address_space(3))) void*)lds,
        16, 0, 0);
}

// ---------------- cast f32 -> bf16 (vectorized) ----------------
__global__ void cast_f32_bf16(const float* __restrict__ in,
                              unsigned short* __restrict__ out, int n) {
    int i = (blockIdx.x * blockDim.x + threadIdx.x) * 4;
    int stride = gridDim.x * blockDim.x * 4;
    for (; i < n; i += stride) {
        float4 v = *(const float4*)(in + i);
        ushort4 o;
        o.x = f2bf(v.x); o.y = f2bf(v.y); o.z = f2bf(v.z); o.w = f2bf(v.w);
        *(ushort4*)(out + i) = o;
    }
}

// ---------------- pre-scale mask by log2(e) ----------------
__global__ void scale_mask(const float* __restrict__ in, float* __restrict__ out) {
    int i = blockIdx.x * 256 + threadIdx.x;   // grid covers BB*SS
    out[i] = in[i] * 1.4426950408889634f;
}

// -------- transpose + cast all 4 weights: W (K x N f32) -> Wt (N x K bf16) --------
__global__ void transpose_cast4(const float* __restrict__ W0, const float* __restrict__ W1,
                                const float* __restrict__ W2, const float* __restrict__ W3,
                                unsigned short* __restrict__ out) {
    const float* in = blockIdx.z == 0 ? W0 : blockIdx.z == 1 ? W1 : blockIdx.z == 2 ? W2 : W3;
    unsigned short* o = out + (size_t)blockIdx.z * ((size_t)HHH * HHH);
    __shared__ float tile[32][33];
    int c0 = blockIdx.x * 32, r0 = blockIdx.y * 32;
    int tx = threadIdx.x, ty = threadIdx.y;   // (32, 8)
    #pragma unroll
    for (int i = 0; i < 32; i += 8)
        tile[ty + i][tx] = in[(size_t)(r0 + ty + i) * HHH + c0 + tx];
    __syncthreads();
    #pragma unroll
    for (int i = 0; i < 32; i += 8)
        o[(size_t)(c0 + ty + i) * HHH + r0 + tx] = f2bf(tile[tx][ty + i]);
}

// ---------------- 2-phase GEMM: C[M,N] = A[M,K] @ Bt[N,K]^T + bias ----------------
// BM=128, BN=256, BK=64. 8 waves (2M x 4N), per-wave 64x64 out, 512 threads.
// Round-9 validated; grid 256 = 8 XCD x 32 (balanced).
template<int MODE>
__global__ __launch_bounds__(512, 2) void gemm8_bf16(
    const unsigned short* __restrict__ A,
    const unsigned short* __restrict__ Bt,
    const float* __restrict__ bias,
    void* __restrict__ Cout,
    int M, int N, int K)
{
    __shared__ __align__(16) unsigned char sm[147456];
    const int tid = threadIdx.x;
    const int wv = tid >> 6, ln = tid & 63;
    const int g = ln >> 4, r = ln & 15;
    const int wr = wv >> 2, wc = wv & 3;

    const int bid = blockIdx.x;
    const int lb = (bid & 7) * 32 + (bid >> 3);
    const int m0 = (lb & 31) * 128;
    const int n0 = (lb >> 5) * 256;

    unsigned srcA[2]; int ldsA[2];
    #pragma unroll
    for (int j = 0; j < 2; ++j) {
        int o = j * 8192 + tid * 16;
        int row = o >> 7;
        int lg = ((o >> 4) & 7) ^ (row & 7);
        srcA[j] = (unsigned)(m0 + row) * K + lg * 8;
        ldsA[j] = o;
    }
    unsigned srcB[4]; int ldsB[4];
    #pragma unroll
    for (int j = 0; j < 4; ++j) {
        int o = j * 8192 + tid * 16;
        int row = o >> 7;
        int lg = ((o >> 4) & 7) ^ (row & 7);
        srcB[j] = (unsigned)(n0 + row) * K + lg * 8;
        ldsB[j] = 16384 + o;
    }

    f32x4 acc[4][4];
    #pragma unroll
    for (int i = 0; i < 4; ++i)
        #pragma unroll
        for (int j = 0; j < 4; ++j)
            acc[i][j] = (f32x4){0.f, 0.f, 0.f, 0.f};

    const int NT = K >> 6;   // 32

    {
        unsigned char* b0 = sm;
        unsigned char* b1 = sm + 49152;
        #pragma unroll
        for (int j = 0; j < 2; ++j) gload16(A + srcA[j], b0 + ldsA[j]);
        #pragma unroll
        for (int j = 0; j < 4; ++j) gload16(Bt + srcB[j], b0 + ldsB[j]);
        #pragma unroll
        for (int j = 0; j < 2; ++j) gload16(A + srcA[j] + 64, b1 + ldsA[j]);
        #pragma unroll
        for (int j = 0; j < 4; ++j) gload16(Bt + srcB[j] + 64, b1 + ldsB[j]);
    }
    asm volatile("s_waitcnt vmcnt(6)" ::: "memory");
    __builtin_amdgcn_s_barrier();

    #define LDA(mi, ks) (*(const bf16x8*)(Ab + (wr * 64 + (mi) * 16 + r) * 128 + \
                         ((((ks) << 2) + g) ^ ((wr * 64 + (mi) * 16 + r) & 7)) * 16))
    #define LDB(ni, ks) (*(const bf16x8*)(Bb + (wc * 64 + (ni) * 16 + r) * 128 + \
                         ((((ks) << 2) + g) ^ ((wc * 64 + (ni) * 16 + r) & 7)) * 16))

    int csel = 0, psel = 2;
    for (int t = 0; t < NT; ++t) {
        const unsigned char* Ab = sm + csel * 49152;
        const unsigned char* Bb = Ab + 16384;
        unsigned char* Pb = sm + psel * 49152;
        const bool pre = (t + 2 < NT);
        const int ko = (t + 2) * 64;

        bf16x8 af[2][2], bfr[4][2];

        // ---- phase A: A rows {0,1} x B cols {0..3}; stage B0,B1,B2
        af[0][0] = LDA(0, 0); af[0][1] = LDA(0, 1);
        af[1][0] = LDA(1, 0); af[1][1] = LDA(1, 1);
        #pragma unroll
        for (int ni = 0; ni < 4; ++ni) { bfr[ni][0] = LDB(ni, 0); bfr[ni][1] = LDB(ni, 1); }
        if (pre) { gload16(Bt + srcB[0] + ko, Pb + ldsB[0]);
                   gload16(Bt + srcB[1] + ko, Pb + ldsB[1]);
                   gload16(Bt + srcB[2] + ko, Pb + ldsB[2]); }
        __builtin_amdgcn_s_barrier();
        asm volatile("s_waitcnt lgkmcnt(0)" ::: "memory");
        __builtin_amdgcn_s_setprio(1);
        #pragma unroll
        for (int mi = 0; mi < 2; ++mi)
            #pragma unroll
            for (int ni = 0; ni < 4; ++ni)
                #pragma unroll
                for (int ks = 0; ks < 2; ++ks)
                    acc[mi][ni] = MFMA16(af[mi][ks], bfr[ni][ks], acc[mi][ni]);
        __builtin_amdgcn_s_setprio(0);
        __builtin_amdgcn_s_barrier();

        // ---- phase B: A rows {2,3} x B cols {0..3} (B held); stage B3,A0,A1
        af[0][0] = LDA(2, 0); af[0][1] = LDA(2, 1);
        af[1][0] = LDA(3, 0); af[1][1] = LDA(3, 1);
        if (pre) { gload16(Bt + srcB[3] + ko, Pb + ldsB[3]);
                   gload16(A + srcA[0] + ko, Pb + ldsA[0]);
                   gload16(A + srcA[1] + ko, Pb + ldsA[1]); }
        __builtin_amdgcn_s_barrier();
        asm volatile("s_waitcnt lgkmcnt(0)" ::: "memory");
        __builtin_amdgcn_s_setprio(1);
        #pragma unroll
        for (int mi = 0; mi < 2; ++mi)
            #pragma unroll
            for (int ni = 0; ni < 4; ++ni)
                #pragma unroll
                for (int ks = 0; ks < 2; ++ks)
                    acc[mi + 2][ni] = MFMA16(af[mi][ks], bfr[ni][ks], acc[mi + 2][ni]);
        __builtin_amdgcn_s_setprio(0);

        if (pre) asm volatile("s_waitcnt vmcnt(6)" ::: "memory");
        else     asm volatile("s_waitcnt vmcnt(0)" ::: "memory");
        __builtin_amdgcn_s_barrier();

        csel = (csel == 2) ? 0 : csel + 1;
        psel = (psel == 2) ? 0 : psel + 1;
    }
    #undef LDA
    #undef LDB

    #pragma unroll
    for (int mt = 0; mt < 4; ++mt) {
        #pragma unroll
        for (int nt = 0; nt < 4; ++nt) {
            int col = n0 + wc * 64 + nt * 16 + r;
            float bvv = bias[col];
            f32x4 a = acc[mt][nt];
            int mrow = m0 + wr * 64 + mt * 16 + g * 4;
            if (MODE == 0) {
                #pragma unroll
                for (int q = 0; q < 4; ++q)
                    ((unsigned short*)Cout)[(size_t)(mrow + q) * N + col] = f2bf(a[q] + bvv);
            } else if (MODE == 2) {
                #pragma unroll
                for (int q = 0; q < 4; ++q)
                    ((float*)Cout)[(size_t)(mrow + q) * N + col] = a[q] + bvv;
            } else {
                int b = mrow >> 11, s0x = mrow & 2047;
                ushort4 o;
                o.x = f2bf(a[0] + bvv); o.y = f2bf(a[1] + bvv);
                o.z = f2bf(a[2] + bvv); o.w = f2bf(a[3] + bvv);
                *(ushort4*)((unsigned short*)Cout + ((size_t)(b * 2048 + col)) * 2048 + s0x) = o;
            }
        }
    }
}

// ---------------- flash attention: in-block KV-split x2, 8 waves, KVBLK=32 dbuf ----
// 512 blocks (2/CU = 16 waves/CU = 4/SIMD). Waves 0-3: keys 0-1023; waves 4-7: keys
// 1024-2047 (per-split dbuf 2x16KB). Per-block global pattern identical to the proven
// 4-wave config (one full K/V read). Final merge in-block via LDS exchange.
__global__ __launch_bounds__(512, 4) void attn_fwd(
    const unsigned short* __restrict__ Q,
    const unsigned short* __restrict__ K,
    const unsigned short* __restrict__ V,
    const float* __restrict__ maskl2,   // mask * log2(e)
    unsigned short* __restrict__ O)
{
    __shared__ __align__(16) unsigned char sm[73728]; // sp0: 0..32K, sp1: 32K..64K, mask @65536
    const int tid = threadIdx.x, wv = tid >> 6, ln = tid & 63;
    const int hi = ln >> 5, qr = ln & 31;
    const int sp = wv >> 2, wq = wv & 3;

    // XCD-bijective swizzle (512 blocks = 8 XCD x 64): XCD owns 4 full heads
    const int bid = blockIdx.x;
    const int lb = (bid & 7) * 64 + (bid >> 3);
    const int qb = lb & 15;
    const int bh = lb >> 4;
    const int h = bh & 15, b = bh >> 4;

    const size_t rowQ0 = (size_t)(b * 2048 + qb * 128 + wq * 32);
    const int kb0 = sp * 1024;   // this split's first key
    const float SCL2 = 0.08838834764831845f * 1.4426950408889634f; // scale*log2e

    // Q fragments FIRST (oldest vmem so compiler's qf-wait doesn't drain staging)
    bf16x8 qf[8];
    #pragma unroll
    for (int ks = 0; ks < 8; ++ks)
        qf[ks] = *(const bf16x8*)(Q + (rowQ0 + qr) * 2048 + h * 128 + ks * 16 + hi * 8);

    // staging precompute (per split): K tile [32][128] (256B rows, 16 granules, ^(row&7));
    //                                 Vt tile [128][32] (64B rows, 4 granules, ^((d>>1)&3))
    unsigned srcK[2], srcV[2];
    int ldsK[2], ldsV[2];
    #pragma unroll
    for (int i = 0; i < 2; ++i) {
        int ch = wq * 2 + i;
        int o = ch * 1024 + ln * 16;
        { int row = o >> 8; int gl = ((o >> 4) & 15) ^ (row & 7);
          srcK[i] = (unsigned)((b * 2048 + kb0 + row) * 2048 + h * 128 + gl * 8);
          ldsK[i] = o; }
        { int d = o >> 6; int gl = ((o >> 4) & 3) ^ ((d >> 1) & 3);
          srcV[i] = (unsigned)((b * 2048 + h * 128 + d) * 2048 + kb0 + gl * 8);
          ldsV[i] = 8192 + o; }
    }

    const int sbase = sp * 32768;
    #define STAGE(t, boff) { \
        _Pragma("unroll") \
        for (int i = 0; i < 2; ++i) { \
            gload16(K + srcK[i] + (unsigned)(t) * (32u * 2048u), sm + sbase + (boff) + ldsK[i]); \
            gload16(V + srcV[i] + (unsigned)(t) * 32u, sm + sbase + (boff) + ldsV[i]); \
        } }

    // mask row -> LDS: 1 gload16 per thread (512 x 16B = 8KB)
    gload16(maskl2 + b * 2048 + tid * 4, sm + 65536 + tid * 16);
    STAGE(0, 0); STAGE(1, 16384);

    f32x16 acc[4];
    #pragma unroll
    for (int i = 0; i < 4; ++i)
        #pragma unroll
        for (int j = 0; j < 16; ++j)
            acc[i][j] = 0.f;
    float mr = -3.0e38f, lr = 0.f;   // per-lane: q-row = qr (within this split)

    const float* ml = (const float*)(sm + 65536) + kb0;

    // wait: qf + mask + tile0 landed (tile1's 4 loads may remain)
    asm volatile("s_waitcnt vmcnt(4)" ::: "memory");
    __builtin_amdgcn_s_barrier();

    for (int t = 0; t < 32; ++t) {
        const unsigned char* Kt = sm + sbase + (t & 1) * 16384;
        const unsigned char* Vt = Kt + 8192;

        // mask values from LDS: key = kb0 + t*32 + rg*8 + hi*4 + q4 (pre-scaled)
        f32x4 mk[4];
        #pragma unroll
        for (int rg = 0; rg < 4; ++rg)
            mk[rg] = *(const f32x4*)(ml + t * 32 + rg * 8 + hi * 4);

        // S^T = K Q^T : two independent 4-deep MFMA chains
        f32x16 sfA, sfB;
        #pragma unroll
        for (int j = 0; j < 16; ++j) { sfA[j] = 0.f; sfB[j] = 0.f; }
        __builtin_amdgcn_s_setprio(1);
        #pragma unroll
        for (int ks = 0; ks < 4; ++ks) {
            int s0 = (2 * ks + hi) ^ (qr & 7);
            bf16x8 kf = *(const bf16x8*)(Kt + qr * 256 + s0 * 16);
            sfA = MFMA32(kf, qf[ks], sfA);
        }
        #pragma unroll
        for (int ks = 4; ks < 8; ++ks) {
            int s0 = (2 * ks + hi) ^ (qr & 7);
            bf16x8 kf = *(const bf16x8*)(Kt + qr * 256 + s0 * 16);
            sfB = MFMA32(kf, qf[ks], sfB);
        }
        __builtin_amdgcn_s_setprio(0);

        // scale + mask (log2 domain)
        float sv[16];
        #pragma unroll
        for (int reg = 0; reg < 16; ++reg)
            sv[reg] = (sfA[reg] + sfB[reg]) * SCL2 + mk[reg >> 2][reg & 3];

        // row max: balanced tree, then cross-half permlane
        float mx[8];
        #pragma unroll
        for (int j = 0; j < 8; ++j)
            mx[j] = fmaxf(sv[2 * j], sv[2 * j + 1]);
        float m01 = fmaxf(fmaxf(fmaxf(mx[0], mx[1]), fmaxf(mx[2], mx[3])),
                          fmaxf(fmaxf(mx[4], mx[5]), fmaxf(mx[6], mx[7])));
        float2 mp = xswap(m01);
        float mt = fmaxf(mp.x, mp.y);

        // defer-max
        float alpha = 1.f;
        int allskip = __all(mt <= mr + 8.f);
        if (!allskip) {
            float nm = fmaxf(mr, mt);
            alpha = __builtin_amdgcn_exp2f(mr - nm);
            mr = nm;
            #pragma unroll
            for (int dblk = 0; dblk < 4; ++dblk)
                #pragma unroll
                for (int reg = 0; reg < 16; ++reg)
                    acc[dblk][reg] *= alpha;
        }

        // P = exp2(S - m), row sum (4 partials), cross-half permlane
        float s0 = 0.f, s1 = 0.f, s2 = 0.f, s3 = 0.f;
        #pragma unroll
        for (int reg = 0; reg < 16; reg += 4) {
            float p0 = __builtin_amdgcn_exp2f(sv[reg + 0] - mr);
            float p1 = __builtin_amdgcn_exp2f(sv[reg + 1] - mr);
            float p2 = __builtin_amdgcn_exp2f(sv[reg + 2] - mr);
            float p3 = __builtin_amdgcn_exp2f(sv[reg + 3] - mr);
            sv[reg + 0] = p0; sv[reg + 1] = p1;
            sv[reg + 2] = p2; sv[reg + 3] = p3;
            s0 += p0; s1 += p1; s2 += p2; s3 += p3;
        }
        float rsl = (s0 + s1) + (s2 + s3);
        float2 rp = xswap(rsl);
        float rs = rp.x + rp.y;
        lr = lr * alpha + rs;

        // P -> PV B-fragments via permlane32_swap (kb16 in {0,1})
        bf16x8 pfr[2];
        #pragma unroll
        for (int kb16 = 0; kb16 < 2; ++kb16) {
            unsigned W00 = packbf(sv[(2*kb16+0)*4 + 0], sv[(2*kb16+0)*4 + 1]);
            unsigned W01 = packbf(sv[(2*kb16+0)*4 + 2], sv[(2*kb16+0)*4 + 3]);
            unsigned W10 = packbf(sv[(2*kb16+1)*4 + 0], sv[(2*kb16+1)*4 + 1]);
            unsigned W11 = packbf(sv[(2*kb16+1)*4 + 2], sv[(2*kb16+1)*4 + 3]);
            pswap(W00, W10);
            pswap(W01, W11);
            union { unsigned w[4]; bf16x8 v; } u;
            u.w[0] = W00; u.w[1] = W01; u.w[2] = W10; u.w[3] = W11;
            pfr[kb16] = u.v;
        }

        // O^T += V^T P^T
        __builtin_amdgcn_s_setprio(1);
        #pragma unroll
        for (int dblk = 0; dblk < 4; ++dblk) {
            int d = dblk * 32 + qr;
            f32x16 a = acc[dblk];
            #pragma unroll
            for (int kb16 = 0; kb16 < 2; ++kb16) {
                int s = (2 * kb16 + hi) ^ ((d >> 1) & 3);
                bf16x8 vf = *(const bf16x8*)(Vt + d * 64 + s * 16);
                a = MFMA32(vf, pfr[kb16], a);
            }
            acc[dblk] = a;
        }
        __builtin_amdgcn_s_setprio(0);

        // tile end: all waves done with buf t&1; refill with t+2; counted wait
        __builtin_amdgcn_s_barrier();
        if (t + 2 < 32) {
            STAGE(t + 2, (t & 1) * 16384);
            asm volatile("s_waitcnt vmcnt(4)" ::: "memory");
        } else {
            asm volatile("s_waitcnt vmcnt(0)" ::: "memory");
        }
        __builtin_amdgcn_s_barrier();
    }
    #undef STAGE

    // -------- in-block combine of the two splits --------
    // sp==1 waves write (m,l,acc) to LDS; sp==0 waves merge + store.
    __syncthreads();
    const int xl = wq * 64 + ln;   // 0..255
    if (sp == 1) {
        ((float2*)(sm + 65536))[xl] = make_float2(mr, lr);
        unsigned char* exb = sm + xl * 256;
        #pragma unroll
        for (int dblk = 0; dblk < 4; ++dblk)
            #pragma unroll
            for (int j = 0; j < 4; ++j) {
                int slot = (dblk * 4 + j) ^ (ln & 15);
                f32x4 vq = { acc[dblk][j * 4 + 0], acc[dblk][j * 4 + 1],
                             acc[dblk][j * 4 + 2], acc[dblk][j * 4 + 3] };
                *(f32x4*)(exb + slot * 16) = vq;
            }
    }
    __syncthreads();
    if (sp == 0) {
        float2 ml1 = ((const float2*)(sm + 65536))[xl];
        float Mx = fmaxf(mr, ml1.x);
        float e0 = __builtin_amdgcn_exp2f(mr - Mx);
        float e1 = __builtin_amdgcn_exp2f(ml1.x - Mx);
        float linv = 1.f / (e0 * lr + e1 * ml1.y);
        e0 *= linv; e1 *= linv;
        const unsigned char* exb = sm + xl * 256;
        unsigned short* orow = O + (rowQ0 + qr) * 2048 + h * 128;
        #pragma unroll
        for (int dblk = 0; dblk < 4; ++dblk)
            #pragma unroll
            for (int rg = 0; rg < 4; ++rg) {
                int slot = (dblk * 4 + rg) ^ (ln & 15);
                f32x4 a1 = *(const f32x4*)(exb + slot * 16);
                float v0 = e0 * acc[dblk][rg * 4 + 0] + e1 * a1[0];
                float v1 = e0 * acc[dblk][rg * 4 + 1] + e1 * a1[1];
                float v2 = e0 * acc[dblk][rg * 4 + 2] + e1 * a1[2];
                float v3 = e0 * acc[dblk][rg * 4 + 3] + e1 * a1[3];
                uint2 o;
                o.x = packbf(v0, v1);
                o.y = packbf(v2, v3);
                *(uint2*)(orow + dblk * 32 + rg * 8 + hi * 4) = o;
            }
    }
}

// ---------------- host launch ----------------
extern "C" void kernel_launch(void* const* d_in, const int* in_sizes, int n_in,
                              void* d_out, int out_size, void* d_ws, size_t ws_size,
                              hipStream_t stream)
{
    (void)in_sizes; (void)n_in; (void)out_size; (void)ws_size;
    const float* x    = (const float*)d_in[0];
    const float* mask = (const float*)d_in[1];
    const float* Wq   = (const float*)d_in[2];
    const float* bq   = (const float*)d_in[3];
    const float* Wk   = (const float*)d_in[4];
    const float* bk   = (const float*)d_in[5];
    const float* Wv   = (const float*)d_in[6];
    const float* bv   = (const float*)d_in[7];
    const float* Wo   = (const float*)d_in[8];
    const float* bo   = (const float*)d_in[9];
    float* out = (float*)d_out;

    char* ws = (char*)d_ws;
    //  0..16  xb (bf16 x)
    // 16..40  Wqt,Wkt,Wvt (Ab reuses 16.., maskl2 reuses 32.. once dead)
    // 40..48  Wot (live to the end)
    // 48..64  Qb   64..80 Kb   80..96 Vtb
    unsigned short* xb  = (unsigned short*)(ws);
    unsigned short* Wqt = (unsigned short*)(ws + (16u << 20));
    unsigned short* Wkt = (unsigned short*)(ws + (24u << 20));
    unsigned short* Wvt = (unsigned short*)(ws + (32u << 20));
    unsigned short* Wot = (unsigned short*)(ws + (40u << 20));
    unsigned short* Qb  = (unsigned short*)(ws + (48u << 20));
    unsigned short* Kb  = (unsigned short*)(ws + (64u << 20));
    unsigned short* Vtb = (unsigned short*)(ws + (80u << 20));
    unsigned short* Ab  = (unsigned short*)(ws + (16u << 20));   // dead Wqt/Wkt
    float*          mkl = (float*)(ws + (32u << 20));            // dead Wvt

    cast_f32_bf16<<<2048, 256, 0, stream>>>(x, xb, MTOT * HHH);
    transpose_cast4<<<dim3(64, 64, 4), dim3(32, 8), 0, stream>>>(Wq, Wk, Wv, Wo, Wqt);

    gemm8_bf16<0><<<256, 512, 0, stream>>>(xb, Wqt, bq, Qb,  MTOT, HHH, HHH);
    gemm8_bf16<0><<<256, 512, 0, stream>>>(xb, Wkt, bk, Kb,  MTOT, HHH, HHH);
    gemm8_bf16<1><<<256, 512, 0, stream>>>(xb, Wvt, bv, Vtb, MTOT, HHH, HHH);

    scale_mask<<<(BB * SS) / 256, 256, 0, stream>>>(mask, mkl);   // after V GEMM (Wvt dead)
    attn_fwd<<<512, 512, 0, stream>>>(Qb, Kb, Vtb, mkl, Ab);

    gemm8_bf16<2><<<256, 512, 0, stream>>>(Ab, Wot, bo, out, MTOT, HHH, HHH);
}

// Round 16
// 276.901 us; speedup vs baseline: 2.1226x; 2.1226x over previous
//
#include <hip/hip_runtime.h>
#include <hip/hip_bf16.h>
#include <stdint.h>

// Problem constants
#define BB   2
#define SS   2048
#define HHH  2048
#define NHH  16
#define HDD  128
#define MTOT 4096   // BB*SS

typedef __bf16 bf16x8 __attribute__((ext_vector_type(8)));
typedef float  f32x4  __attribute__((ext_vector_type(4)));
typedef float  f32x16 __attribute__((ext_vector_type(16)));

#define MFMA16(a, b, c) __builtin_amdgcn_mfma_f32_16x16x32_bf16((a), (b), (c), 0, 0, 0)
#define MFMA32(a, b, c) __builtin_amdgcn_mfma_f32_32x32x16_bf16((a), (b), (c), 0, 0, 0)

__device__ __forceinline__ unsigned short f2bf(float f) {
    union { float f; unsigned u; } v; v.f = f;
    unsigned r = v.u + 0x7FFFu + ((v.u >> 16) & 1u);   // RNE
    return (unsigned short)(r >> 16);
}

__device__ __forceinline__ unsigned packbf(float a, float b) {
    union { __bf16 h[2]; unsigned u; } p;
    p.h[0] = (__bf16)a; p.h[1] = (__bf16)b;
    return p.u;
}

// v_permlane32_swap_b32: a' = [a.lo32, b.lo32], b' = [a.hi32, b.hi32]
__device__ __forceinline__ void pswap(unsigned &a, unsigned &b) {
    asm("v_permlane32_swap_b32 %0, %1" : "+v"(a), "+v"(b));
}

// cross-half (lane ^ 32) pair: returns {own-half view, other-half view}
__device__ __forceinline__ float2 xswap(float x) {
    unsigned a = __builtin_bit_cast(unsigned, x);
    unsigned b;
    asm("v_mov_b32 %0, %1" : "=v"(b) : "v"(a));   // force distinct register
    asm("v_permlane32_swap_b32 %0, %1" : "+v"(a), "+v"(b));
    return make_float2(__builtin_bit_cast(float, a), __builtin_bit_cast(float, b));
}

// async global->LDS, 16B per lane. LDS dest is wave-uniform base + lane*16.
__device__ __forceinline__ void gload16(const void* src, void* lds) {
    __builtin_amdgcn_global_load_lds(
        (__attribute__((address_space(1))) void*)src,
        (__attribute__((address_space(3))) void*)lds,
        16, 0, 0);
}

// ------- cast f32 -> bf16 (vectorized) + mask pre-scale (blocks >= 2048) -------
__global__ void cast_f32_bf16(const float* __restrict__ in,
                              unsigned short* __restrict__ out,
                              const float* __restrict__ mask,
                              float* __restrict__ mkl) {
    const int b = blockIdx.x;
    if (b >= 2048) {
        int i = (b - 2048) * 256 + threadIdx.x;   // 4 blocks cover BB*SS = 4096
        mkl[i] = mask[i] * 1.4426950408889634f;
        return;
    }
    const int n = MTOT * HHH;
    const int stride = 2048 * 256 * 4;            // cast blocks only
    for (int i = (b * 256 + threadIdx.x) * 4; i < n; i += stride) {
        float4 v = *(const float4*)(in + i);
        ushort4 o;
        o.x = f2bf(v.x); o.y = f2bf(v.y); o.z = f2bf(v.z); o.w = f2bf(v.w);
        *(ushort4*)(out + i) = o;
    }
}

// -------- transpose + cast all 4 weights: W (K x N f32) -> Wt (N x K bf16) --------
__global__ void transpose_cast4(const float* __restrict__ W0, const float* __restrict__ W1,
                                const float* __restrict__ W2, const float* __restrict__ W3,
                                unsigned short* __restrict__ out) {
    const float* in = blockIdx.z == 0 ? W0 : blockIdx.z == 1 ? W1 : blockIdx.z == 2 ? W2 : W3;
    unsigned short* o = out + (size_t)blockIdx.z * ((size_t)HHH * HHH);
    __shared__ float tile[32][33];
    int c0 = blockIdx.x * 32, r0 = blockIdx.y * 32;
    int tx = threadIdx.x, ty = threadIdx.y;   // (32, 8)
    #pragma unroll
    for (int i = 0; i < 32; i += 8)
        tile[ty + i][tx] = in[(size_t)(r0 + ty + i) * HHH + c0 + tx];
    __syncthreads();
    #pragma unroll
    for (int i = 0; i < 32; i += 8)
        o[(size_t)(c0 + ty + i) * HHH + r0 + tx] = f2bf(tile[tx][ty + i]);
}

// ---------------- 2-phase GEMM: C[M,N] = A[M,K] @ Bt[N,K]^T + bias ----------------
// BM=128, BN=256, BK=64. 8 waves (2M x 4N), per-wave 64x64 out, 512 threads.
// Round-9 validated; grid 256 = 8 XCD x 32 (balanced).
template<int MODE>
__global__ __launch_bounds__(512, 2) void gemm8_bf16(
    const unsigned short* __restrict__ A,
    const unsigned short* __restrict__ Bt,
    const float* __restrict__ bias,
    void* __restrict__ Cout,
    int M, int N, int K)
{
    __shared__ __align__(16) unsigned char sm[147456];
    const int tid = threadIdx.x;
    const int wv = tid >> 6, ln = tid & 63;
    const int g = ln >> 4, r = ln & 15;
    const int wr = wv >> 2, wc = wv & 3;

    const int bid = blockIdx.x;
    const int lb = (bid & 7) * 32 + (bid >> 3);
    const int m0 = (lb & 31) * 128;
    const int n0 = (lb >> 5) * 256;

    unsigned srcA[2]; int ldsA[2];
    #pragma unroll
    for (int j = 0; j < 2; ++j) {
        int o = j * 8192 + tid * 16;
        int row = o >> 7;
        int lg = ((o >> 4) & 7) ^ (row & 7);
        srcA[j] = (unsigned)(m0 + row) * K + lg * 8;
        ldsA[j] = o;
    }
    unsigned srcB[4]; int ldsB[4];
    #pragma unroll
    for (int j = 0; j < 4; ++j) {
        int o = j * 8192 + tid * 16;
        int row = o >> 7;
        int lg = ((o >> 4) & 7) ^ (row & 7);
        srcB[j] = (unsigned)(n0 + row) * K + lg * 8;
        ldsB[j] = 16384 + o;
    }

    f32x4 acc[4][4];
    #pragma unroll
    for (int i = 0; i < 4; ++i)
        #pragma unroll
        for (int j = 0; j < 4; ++j)
            acc[i][j] = (f32x4){0.f, 0.f, 0.f, 0.f};

    const int NT = K >> 6;   // 32

    {
        unsigned char* b0 = sm;
        unsigned char* b1 = sm + 49152;
        #pragma unroll
        for (int j = 0; j < 2; ++j) gload16(A + srcA[j], b0 + ldsA[j]);
        #pragma unroll
        for (int j = 0; j < 4; ++j) gload16(Bt + srcB[j], b0 + ldsB[j]);
        #pragma unroll
        for (int j = 0; j < 2; ++j) gload16(A + srcA[j] + 64, b1 + ldsA[j]);
        #pragma unroll
        for (int j = 0; j < 4; ++j) gload16(Bt + srcB[j] + 64, b1 + ldsB[j]);
    }
    asm volatile("s_waitcnt vmcnt(6)" ::: "memory");
    __builtin_amdgcn_s_barrier();

    #define LDA(mi, ks) (*(const bf16x8*)(Ab + (wr * 64 + (mi) * 16 + r) * 128 + \
                         ((((ks) << 2) + g) ^ ((wr * 64 + (mi) * 16 + r) & 7)) * 16))
    #define LDB(ni, ks) (*(const bf16x8*)(Bb + (wc * 64 + (ni) * 16 + r) * 128 + \
                         ((((ks) << 2) + g) ^ ((wc * 64 + (ni) * 16 + r) & 7)) * 16))

    int csel = 0, psel = 2;
    for (int t = 0; t < NT; ++t) {
        const unsigned char* Ab = sm + csel * 49152;
        const unsigned char* Bb = Ab + 16384;
        unsigned char* Pb = sm + psel * 49152;
        const bool pre = (t + 2 < NT);
        const int ko = (t + 2) * 64;

        bf16x8 af[2][2], bfr[4][2];

        // ---- phase A: A rows {0,1} x B cols {0..3}; stage B0,B1,B2
        af[0][0] = LDA(0, 0); af[0][1] = LDA(0, 1);
        af[1][0] = LDA(1, 0); af[1][1] = LDA(1, 1);
        #pragma unroll
        for (int ni = 0; ni < 4; ++ni) { bfr[ni][0] = LDB(ni, 0); bfr[ni][1] = LDB(ni, 1); }
        if (pre) { gload16(Bt + srcB[0] + ko, Pb + ldsB[0]);
                   gload16(Bt + srcB[1] + ko, Pb + ldsB[1]);
                   gload16(Bt + srcB[2] + ko, Pb + ldsB[2]); }
        __builtin_amdgcn_s_barrier();
        asm volatile("s_waitcnt lgkmcnt(0)" ::: "memory");
        __builtin_amdgcn_s_setprio(1);
        #pragma unroll
        for (int mi = 0; mi < 2; ++mi)
            #pragma unroll
            for (int ni = 0; ni < 4; ++ni)
                #pragma unroll
                for (int ks = 0; ks < 2; ++ks)
                    acc[mi][ni] = MFMA16(af[mi][ks], bfr[ni][ks], acc[mi][ni]);
        __builtin_amdgcn_s_setprio(0);
        __builtin_amdgcn_s_barrier();

        // ---- phase B: A rows {2,3} x B cols {0..3} (B held); stage B3,A0,A1
        af[0][0] = LDA(2, 0); af[0][1] = LDA(2, 1);
        af[1][0] = LDA(3, 0); af[1][1] = LDA(3, 1);
        if (pre) { gload16(Bt + srcB[3] + ko, Pb + ldsB[3]);
                   gload16(A + srcA[0] + ko, Pb + ldsA[0]);
                   gload16(A + srcA[1] + ko, Pb + ldsA[1]); }
        __builtin_amdgcn_s_barrier();
        asm volatile("s_waitcnt lgkmcnt(0)" ::: "memory");
        __builtin_amdgcn_s_setprio(1);
        #pragma unroll
        for (int mi = 0; mi < 2; ++mi)
            #pragma unroll
            for (int ni = 0; ni < 4; ++ni)
                #pragma unroll
                for (int ks = 0; ks < 2; ++ks)
                    acc[mi + 2][ni] = MFMA16(af[mi][ks], bfr[ni][ks], acc[mi + 2][ni]);
        __builtin_amdgcn_s_setprio(0);

        if (pre) asm volatile("s_waitcnt vmcnt(6)" ::: "memory");
        else     asm volatile("s_waitcnt vmcnt(0)" ::: "memory");
        __builtin_amdgcn_s_barrier();

        csel = (csel == 2) ? 0 : csel + 1;
        psel = (psel == 2) ? 0 : psel + 1;
    }
    #undef LDA
    #undef LDB

    #pragma unroll
    for (int mt = 0; mt < 4; ++mt) {
        #pragma unroll
        for (int nt = 0; nt < 4; ++nt) {
            int col = n0 + wc * 64 + nt * 16 + r;
            float bvv = bias[col];
            f32x4 a = acc[mt][nt];
            int mrow = m0 + wr * 64 + mt * 16 + g * 4;
            if (MODE == 0) {
                #pragma unroll
                for (int q = 0; q < 4; ++q)
                    ((unsigned short*)Cout)[(size_t)(mrow + q) * N + col] = f2bf(a[q] + bvv);
            } else if (MODE == 2) {
                #pragma unroll
                for (int q = 0; q < 4; ++q)
                    ((float*)Cout)[(size_t)(mrow + q) * N + col] = a[q] + bvv;
            } else {
                int b = mrow >> 11, s0x = mrow & 2047;
                ushort4 o;
                o.x = f2bf(a[0] + bvv); o.y = f2bf(a[1] + bvv);
                o.z = f2bf(a[2] + bvv); o.w = f2bf(a[3] + bvv);
                *(ushort4*)((unsigned short*)Cout + ((size_t)(b * 2048 + col)) * 2048 + s0x) = o;
            }
        }
    }
}

// ---------------- flash attention: KVBLK=64, 2-buf counted pipeline, mask in LDS ----------------
// Round-10 validated (104 µs, VGPR 104). 512 blocks (2/CU), 4 waves x 32 q-rows.
// Dbuf {K[64][128], Vt[128][64]} (2 x 32KB) + mask row (8KB) = 72KB. Zero loop VMEM
// except 8 STAGE loads; stage-after-barrier + counted vmcnt(8).
__global__ __launch_bounds__(256, 2) void attn_fwd(
    const unsigned short* __restrict__ Q,
    const unsigned short* __restrict__ K,
    const unsigned short* __restrict__ V,
    const float* __restrict__ maskl2,   // mask * log2(e)
    unsigned short* __restrict__ O)
{
    __shared__ __align__(16) unsigned char sm[73728]; // 2 x 32KB KV bufs + 8KB mask @65536
    const int tid = threadIdx.x, wv = tid >> 6, ln = tid & 63;
    const int hi = ln >> 5, qr = ln & 31;

    // XCD-bijective swizzle (512 blocks = 8 XCD x 64): XCD owns 4 full heads
    const int bid = blockIdx.x;
    const int lb = (bid & 7) * 64 + (bid >> 3);
    const int qb = lb & 15;
    const int bh = lb >> 4;
    const int h = bh & 15, b = bh >> 4;

    const size_t rowQ0 = (size_t)(b * 2048 + qb * 128 + wv * 32);
    const float SCL2 = 0.08838834764831845f * 1.4426950408889634f; // scale*log2e

    // staging precompute: K tile [64][128] (256B rows, 16 granules, ^(row&7));
    //                     Vt tile [128][64] (128B rows, 8 granules, ^(d&7))
    unsigned srcK[4], srcV[4];
    int ldsK[4], ldsV[4];
    #pragma unroll
    for (int i = 0; i < 4; ++i) {
        int ch = wv * 4 + i;
        int o = ch * 1024 + ln * 16;
        { int row = o >> 8; int gl = ((o >> 4) & 15) ^ (row & 7);
          srcK[i] = (unsigned)((b * 2048 + row) * 2048 + h * 128 + gl * 8);
          ldsK[i] = o; }
        { int d = o >> 7; int gl = ((o >> 4) & 7) ^ (d & 7);
          srcV[i] = (unsigned)((b * 2048 + h * 128 + d) * 2048 + gl * 8);
          ldsV[i] = 16384 + o; }
    }

    #define STAGE(t, base) { \
        _Pragma("unroll") \
        for (int i = 0; i < 4; ++i) { \
            gload16(K + srcK[i] + (unsigned)(t) * (64u * 2048u), sm + (base) + ldsK[i]); \
            gload16(V + srcV[i] + (unsigned)(t) * 64u, sm + (base) + ldsV[i]); \
        } }

    // prologue: mask row -> LDS first (oldest), then tiles 0,1
    #pragma unroll
    for (int i = 0; i < 2; ++i)
        gload16(maskl2 + b * 2048 + wv * 512 + i * 256 + ln * 4,
                sm + 65536 + wv * 2048 + i * 1024);
    STAGE(0, 0); STAGE(1, 32768);

    // Q fragments (B-operand): col = qr, k = hi*8+j, 8 k-steps of 16
    bf16x8 qf[8];
    #pragma unroll
    for (int ks = 0; ks < 8; ++ks)
        qf[ks] = *(const bf16x8*)(Q + (rowQ0 + qr) * 2048 + h * 128 + ks * 16 + hi * 8);

    f32x16 acc[4];
    #pragma unroll
    for (int i = 0; i < 4; ++i)
        #pragma unroll
        for (int j = 0; j < 16; ++j)
            acc[i][j] = 0.f;
    float mr = -3.0e38f, lr = 0.f;   // per-lane: q-row = qr

    const float* ml = (const float*)(sm + 65536);

    // of 18 outstanding (2 mask + 8 + 8), wait until only 8 (tile 1) remain
    asm volatile("s_waitcnt vmcnt(8)" ::: "memory");
    __builtin_amdgcn_s_barrier();

    for (int t = 0; t < 32; ++t) {
        const unsigned char* Kt = sm + (t & 1) * 32768;
        const unsigned char* Vt = Kt + 16384;

        // mask values from LDS: key = t*64 + kb2*32 + rg*8 + hi*4 + q4 (pre-scaled)
        f32x4 mk[2][4];
        #pragma unroll
        for (int kb2 = 0; kb2 < 2; ++kb2)
            #pragma unroll
            for (int rg = 0; rg < 4; ++rg)
                mk[kb2][rg] = *(const f32x4*)(ml + t * 64 + kb2 * 32 + rg * 8 + hi * 4);

        // S^T = K Q^T : two independent 8-deep chains (keys 0-31 / 32-63)
        f32x16 sf0, sf1;
        #pragma unroll
        for (int j = 0; j < 16; ++j) { sf0[j] = 0.f; sf1[j] = 0.f; }
        __builtin_amdgcn_s_setprio(1);
        #pragma unroll
        for (int ks = 0; ks < 8; ++ks) {
            int row0 = qr, row1 = 32 + qr;
            int s0 = ((2 * ks + hi) ^ (row0 & 7));
            int s1 = ((2 * ks + hi) ^ (row1 & 7));
            bf16x8 kf0 = *(const bf16x8*)(Kt + row0 * 256 + s0 * 16);
            bf16x8 kf1 = *(const bf16x8*)(Kt + row1 * 256 + s1 * 16);
            sf0 = MFMA32(kf0, qf[ks], sf0);
            sf1 = MFMA32(kf1, qf[ks], sf1);
        }
        __builtin_amdgcn_s_setprio(0);

        // scale + mask (log2 domain; mask pre-scaled)
        float sv[2][16];
        #pragma unroll
        for (int reg = 0; reg < 16; ++reg) {
            sv[0][reg] = sf0[reg] * SCL2 + mk[0][reg >> 2][reg & 3];
            sv[1][reg] = sf1[reg] * SCL2 + mk[1][reg >> 2][reg & 3];
        }

        // row max: balanced tree over 32 in-lane values, then cross-half permlane
        float mx[8];
        #pragma unroll
        for (int j = 0; j < 8; ++j)
            mx[j] = fmaxf(fmaxf(sv[0][2*j], sv[0][2*j+1]),
                          fmaxf(sv[1][2*j], sv[1][2*j+1]));
        float m01 = fmaxf(fmaxf(fmaxf(mx[0], mx[1]), fmaxf(mx[2], mx[3])),
                          fmaxf(fmaxf(mx[4], mx[5]), fmaxf(mx[6], mx[7])));
        float2 mp = xswap(m01);
        float mt = fmaxf(mp.x, mp.y);

        // defer-max
        float alpha = 1.f;
        int allskip = __all(mt <= mr + 8.f);
        if (!allskip) {
            float nm = fmaxf(mr, mt);
            alpha = __builtin_amdgcn_exp2f(mr - nm);
            mr = nm;
            #pragma unroll
            for (int dblk = 0; dblk < 4; ++dblk)
                #pragma unroll
                for (int reg = 0; reg < 16; ++reg)
                    acc[dblk][reg] *= alpha;
        }

        // P = exp2(S - m), row sum (4 partials), cross-half permlane
        float s0 = 0.f, s1 = 0.f, s2 = 0.f, s3 = 0.f;
        #pragma unroll
        for (int kb2 = 0; kb2 < 2; ++kb2)
            #pragma unroll
            for (int reg = 0; reg < 16; reg += 4) {
                float p0 = __builtin_amdgcn_exp2f(sv[kb2][reg + 0] - mr);
                float p1 = __builtin_amdgcn_exp2f(sv[kb2][reg + 1] - mr);
                float p2 = __builtin_amdgcn_exp2f(sv[kb2][reg + 2] - mr);
                float p3 = __builtin_amdgcn_exp2f(sv[kb2][reg + 3] - mr);
                sv[kb2][reg + 0] = p0; sv[kb2][reg + 1] = p1;
                sv[kb2][reg + 2] = p2; sv[kb2][reg + 3] = p3;
                s0 += p0; s1 += p1; s2 += p2; s3 += p3;
            }
        float rsl = (s0 + s1) + (s2 + s3);
        float2 rp = xswap(rsl);
        float rs = rp.x + rp.y;
        lr = lr * alpha + rs;

        // P -> PV B-fragments via permlane32_swap (kb16 in {0..3})
        bf16x8 pfr[4];
        #pragma unroll
        for (int kb16 = 0; kb16 < 4; ++kb16) {
            const int kb2 = kb16 >> 1, i2 = kb16 & 1;
            float* pv = sv[kb2];
            unsigned W00 = packbf(pv[(2*i2+0)*4 + 0], pv[(2*i2+0)*4 + 1]);
            unsigned W01 = packbf(pv[(2*i2+0)*4 + 2], pv[(2*i2+0)*4 + 3]);
            unsigned W10 = packbf(pv[(2*i2+1)*4 + 0], pv[(2*i2+1)*4 + 1]);
            unsigned W11 = packbf(pv[(2*i2+1)*4 + 2], pv[(2*i2+1)*4 + 3]);
            pswap(W00, W10);
            pswap(W01, W11);
            union { unsigned w[4]; bf16x8 v; } u;
            u.w[0] = W00; u.w[1] = W01; u.w[2] = W10; u.w[3] = W11;
            pfr[kb16] = u.v;
        }

        // O^T += V^T P^T
        __builtin_amdgcn_s_setprio(1);
        #pragma unroll
        for (int dblk = 0; dblk < 4; ++dblk) {
            int d = dblk * 32 + qr;
            f32x16 a = acc[dblk];
            #pragma unroll
            for (int kb16 = 0; kb16 < 4; ++kb16) {
                int s = ((2 * kb16 + hi) ^ (d & 7));
                bf16x8 vf = *(const bf16x8*)(Vt + d * 128 + s * 16);
                a = MFMA32(vf, pfr[kb16], a);
            }
            acc[dblk] = a;
        }
        __builtin_amdgcn_s_setprio(0);

        // tile end: all waves done reading buf t&1, refill it with t+2, then
        // counted wait -> t+1's 8 loads (oldest) complete; t+2's 8 stay in flight
        __builtin_amdgcn_s_barrier();
        if (t + 2 < 32) {
            STAGE(t + 2, (t & 1) * 32768);
            asm volatile("s_waitcnt vmcnt(8)" ::: "memory");
        } else {
            asm volatile("s_waitcnt vmcnt(0)" ::: "memory");
        }
        __builtin_amdgcn_s_barrier();
    }

    // epilogue: O[qrow][d], d = dblk*32 + rg*8 + 4*hi + q4; per-lane 1/l
    float linv = 1.f / lr;
    unsigned short* orow = O + (rowQ0 + qr) * 2048 + h * 128;
    #pragma unroll
    for (int dblk = 0; dblk < 4; ++dblk)
        #pragma unroll
        for (int rg = 0; rg < 4; ++rg) {
            float v0 = acc[dblk][rg * 4 + 0] * linv;
            float v1 = acc[dblk][rg * 4 + 1] * linv;
            float v2 = acc[dblk][rg * 4 + 2] * linv;
            float v3 = acc[dblk][rg * 4 + 3] * linv;
            uint2 o;
            o.x = packbf(v0, v1);
            o.y = packbf(v2, v3);
            *(uint2*)(orow + dblk * 32 + rg * 8 + hi * 4) = o;
        }
    #undef STAGE
}

// ---------------- host launch ----------------
extern "C" void kernel_launch(void* const* d_in, const int* in_sizes, int n_in,
                              void* d_out, int out_size, void* d_ws, size_t ws_size,
                              hipStream_t stream)
{
    (void)in_sizes; (void)n_in; (void)out_size; (void)ws_size;
    const float* x    = (const float*)d_in[0];
    const float* mask = (const float*)d_in[1];
    const float* Wq   = (const float*)d_in[2];
    const float* bq   = (const float*)d_in[3];
    const float* Wk   = (const float*)d_in[4];
    const float* bk   = (const float*)d_in[5];
    const float* Wv   = (const float*)d_in[6];
    const float* bv   = (const float*)d_in[7];
    const float* Wo   = (const float*)d_in[8];
    const float* bo   = (const float*)d_in[9];
    float* out = (float*)d_out;

    char* ws = (char*)d_ws;
    //  0..16  xb (bf16 x)
    // 16..40  Wqt,Wkt,Wvt (Ab reuses 16.. once dead)
    // 40..48  Wot (live to the end)
    // 48..64  Qb   64..80 Kb   80..96 Vtb
    // mkl (16KB) lives in d_out: written by cast kernel, consumed by attn,
    // overwritten by gemmO (which runs strictly after attn on this stream).
    unsigned short* xb  = (unsigned short*)(ws);
    unsigned short* Wqt = (unsigned short*)(ws + (16u << 20));
    unsigned short* Wkt = (unsigned short*)(ws + (24u << 20));
    unsigned short* Wvt = (unsigned short*)(ws + (32u << 20));
    unsigned short* Wot = (unsigned short*)(ws + (40u << 20));
    unsigned short* Qb  = (unsigned short*)(ws + (48u << 20));
    unsigned short* Kb  = (unsigned short*)(ws + (64u << 20));
    unsigned short* Vtb = (unsigned short*)(ws + (80u << 20));
    unsigned short* Ab  = (unsigned short*)(ws + (16u << 20));   // dead Wqt/Wkt
    float*          mkl = out;                                   // scratch in d_out

    cast_f32_bf16<<<2052, 256, 0, stream>>>(x, xb, mask, mkl);
    transpose_cast4<<<dim3(64, 64, 4), dim3(32, 8), 0, stream>>>(Wq, Wk, Wv, Wo, Wqt);

    gemm8_bf16<0><<<256, 512, 0, stream>>>(xb, Wqt, bq, Qb,  MTOT, HHH, HHH);
    gemm8_bf16<0><<<256, 512, 0, stream>>>(xb, Wkt, bk, Kb,  MTOT, HHH, HHH);
    gemm8_bf16<1><<<256, 512, 0, stream>>>(xb, Wvt, bv, Vtb, MTOT, HHH, HHH);

    attn_fwd<<<512, 256, 0, stream>>>(Qb, Kb, Vtb, mkl, Ab);

    gemm8_bf16<2><<<256, 512, 0, stream>>>(Ab, Wot, bo, out, MTOT, HHH, HHH);
}

// Round 17
// 263.352 us; speedup vs baseline: 2.2318x; 1.0514x over previous
//
#include <hip/hip_runtime.h>
#include <hip/hip_bf16.h>
#include <stdint.h>

// Problem constants
#define BB   2
#define SS   2048
#define HHH  2048
#define NHH  16
#define HDD  128
#define MTOT 4096   // BB*SS

typedef __bf16 bf16x8 __attribute__((ext_vector_type(8)));
typedef float  f32x4  __attribute__((ext_vector_type(4)));
typedef float  f32x16 __attribute__((ext_vector_type(16)));

#define MFMA16(a, b, c) __builtin_amdgcn_mfma_f32_16x16x32_bf16((a), (b), (c), 0, 0, 0)
#define MFMA32(a, b, c) __builtin_amdgcn_mfma_f32_32x32x16_bf16((a), (b), (c), 0, 0, 0)

__device__ __forceinline__ unsigned short f2bf(float f) {
    union { float f; unsigned u; } v; v.f = f;
    unsigned r = v.u + 0x7FFFu + ((v.u >> 16) & 1u);   // RNE
    return (unsigned short)(r >> 16);
}

__device__ __forceinline__ unsigned packbf(float a, float b) {
    union { __bf16 h[2]; unsigned u; } p;
    p.h[0] = (__bf16)a; p.h[1] = (__bf16)b;
    return p.u;
}

// v_permlane32_swap_b32: a' = [a.lo32, b.lo32], b' = [a.hi32, b.hi32]
__device__ __forceinline__ void pswap(unsigned &a, unsigned &b) {
    asm("v_permlane32_swap_b32 %0, %1" : "+v"(a), "+v"(b));
}

// cross-half (lane ^ 32) pair: returns {own-half view, other-half view}
__device__ __forceinline__ float2 xswap(float x) {
    unsigned a = __builtin_bit_cast(unsigned, x);
    unsigned b;
    asm("v_mov_b32 %0, %1" : "=v"(b) : "v"(a));   // force distinct register
    asm("v_permlane32_swap_b32 %0, %1" : "+v"(a), "+v"(b));
    return make_float2(__builtin_bit_cast(float, a), __builtin_bit_cast(float, b));
}

// async global->LDS, 16B per lane. LDS dest is wave-uniform base + lane*16.
__device__ __forceinline__ void gload16(const void* src, void* lds) {
    __builtin_amdgcn_global_load_lds(
        (__attribute__((address_space(1))) void*)src,
        (__attribute__((address_space(3))) void*)lds,
        16, 0, 0);
}

// ------- cast f32 -> bf16 (vectorized) + mask pre-scale (blocks >= 2048) -------
__global__ void cast_f32_bf16(const float* __restrict__ in,
                              unsigned short* __restrict__ out,
                              const float* __restrict__ mask,
                              float* __restrict__ mkl) {
    const int b = blockIdx.x;
    if (b >= 2048) {
        int i = (b - 2048) * 256 + threadIdx.x;   // 4 blocks cover BB*SS = 4096
        mkl[i] = mask[i] * 1.4426950408889634f;
        return;
    }
    const int n = MTOT * HHH;
    const int stride = 2048 * 256 * 4;            // cast blocks only
    for (int i = (b * 256 + threadIdx.x) * 4; i < n; i += stride) {
        float4 v = *(const float4*)(in + i);
        ushort4 o;
        o.x = f2bf(v.x); o.y = f2bf(v.y); o.z = f2bf(v.z); o.w = f2bf(v.w);
        *(ushort4*)(out + i) = o;
    }
}

// -------- transpose + cast all 4 weights: W (K x N f32) -> Wt (N x K bf16) --------
__global__ void transpose_cast4(const float* __restrict__ W0, const float* __restrict__ W1,
                                const float* __restrict__ W2, const float* __restrict__ W3,
                                unsigned short* __restrict__ out) {
    const float* in = blockIdx.z == 0 ? W0 : blockIdx.z == 1 ? W1 : blockIdx.z == 2 ? W2 : W3;
    unsigned short* o = out + (size_t)blockIdx.z * ((size_t)HHH * HHH);
    __shared__ float tile[32][33];
    int c0 = blockIdx.x * 32, r0 = blockIdx.y * 32;
    int tx = threadIdx.x, ty = threadIdx.y;   // (32, 8)
    #pragma unroll
    for (int i = 0; i < 32; i += 8)
        tile[ty + i][tx] = in[(size_t)(r0 + ty + i) * HHH + c0 + tx];
    __syncthreads();
    #pragma unroll
    for (int i = 0; i < 32; i += 8)
        o[(size_t)(c0 + ty + i) * HHH + r0 + tx] = f2bf(tile[tx][ty + i]);
}

// ---------------- fused QK GEMM, 256x256 tile, 4-phase interleave ----------------
// BM=BN=256, BK=64, 8 waves (2M x 4N), per-wave 128x64, acc[8][4]. LDS dbuf 2x64KB.
// Phases: TL(A_top,B_L) -> TR(B_R) -> BR(A_bot) -> BL(B_L re-read), 16 MFMA each.
// Staging of tile t+2 into the progressively-freed current buffer: A_top @P2,
// A_bot @P3, B @tile-end; counted vmcnt(8) (t+2 in flight, t+1 proven landed).
// N = 4096 (Q|K), grid 256 = 8 XCD x 32 (bijective, 1 block/CU balanced).
__global__ __launch_bounds__(512, 2) void gemmQK(
    const unsigned short* __restrict__ A,
    const unsigned short* __restrict__ Bt,     // Wqt|Wkt contiguous, 4096 x 2048
    const float* __restrict__ bq,
    const float* __restrict__ bk,
    unsigned short* __restrict__ Qb,
    unsigned short* __restrict__ Kb)
{
    __shared__ __align__(16) unsigned char sm[131072];
    const int tid = threadIdx.x;
    const int wv = tid >> 6, ln = tid & 63;
    const int g = ln >> 4, r = ln & 15;
    const int wr = wv >> 2, wc = wv & 3;
    const int K = HHH;

    const int bid = blockIdx.x;
    const int lb = (bid & 7) * 32 + (bid >> 3);
    const int m0 = (lb & 15) * 256;
    const int n0 = (lb >> 4) * 256;

    // staging: 256x64 tiles, 128B rows = 8 granules, phys granule = logical^(row&7)
    unsigned srcA[4], srcB[4];
    int ldsA[4], ldsB[4];
    #pragma unroll
    for (int j = 0; j < 4; ++j) {
        int o = j * 8192 + tid * 16;
        int row = o >> 7;
        int lg = ((o >> 4) & 7) ^ (row & 7);
        srcA[j] = (unsigned)(m0 + row) * K + lg * 8;
        srcB[j] = (unsigned)(n0 + row) * K + lg * 8;
        ldsA[j] = o;
        ldsB[j] = 32768 + o;
    }

    f32x4 acc[8][4];
    #pragma unroll
    for (int i = 0; i < 8; ++i)
        #pragma unroll
        for (int j = 0; j < 4; ++j)
            acc[i][j] = (f32x4){0.f, 0.f, 0.f, 0.f};

    // prologue: tiles 0 (buf0) and 1 (buf1)
    #pragma unroll
    for (int j = 0; j < 4; ++j) { gload16(A + srcA[j], sm + ldsA[j]);
                                  gload16(Bt + srcB[j], sm + ldsB[j]); }
    #pragma unroll
    for (int j = 0; j < 4; ++j) { gload16(A + srcA[j] + 64, sm + 65536 + ldsA[j]);
                                  gload16(Bt + srcB[j] + 64, sm + 65536 + ldsB[j]); }
    asm volatile("s_waitcnt vmcnt(8)" ::: "memory");
    __builtin_amdgcn_s_barrier();

    #define LDA(mi, ks) (*(const bf16x8*)(Ab + (wr * 128 + (mi) * 16 + r) * 128 + \
                         ((((ks) << 2) + g) ^ ((wr * 128 + (mi) * 16 + r) & 7)) * 16))
    #define LDB(ni, ks) (*(const bf16x8*)(Bb + (wc * 64 + (ni) * 16 + r) * 128 + \
                         ((((ks) << 2) + g) ^ ((wc * 64 + (ni) * 16 + r) & 7)) * 16))

    for (int t = 0; t < 32; ++t) {
        const int base = (t & 1) * 65536;
        const unsigned char* Ab = sm + base;
        const unsigned char* Bb = Ab + 32768;
        unsigned char* Pb = sm + base;       // t+2 lands in the buffer being freed
        const bool pre = (t + 2 < 32);
        const int ko = (t + 2) * 64;

        bf16x8 af[4][2], bfr[2][2];

        // ---- P0 (TL): read A_top(8) + B_L(4); MFMA mt0-3 x nt0-1
        #pragma unroll
        for (int mi = 0; mi < 4; ++mi) { af[mi][0] = LDA(mi, 0); af[mi][1] = LDA(mi, 1); }
        bfr[0][0] = LDB(0, 0); bfr[0][1] = LDB(0, 1);
        bfr[1][0] = LDB(1, 0); bfr[1][1] = LDB(1, 1);
        __builtin_amdgcn_s_barrier();
        asm volatile("s_waitcnt lgkmcnt(0)" ::: "memory");
        __builtin_amdgcn_s_setprio(1);
        #pragma unroll
        for (int mi = 0; mi < 4; ++mi)
            #pragma unroll
            for (int ni = 0; ni < 2; ++ni)
                #pragma unroll
                for (int ks = 0; ks < 2; ++ks)
                    acc[mi][ni] = MFMA16(af[mi][ks], bfr[ni][ks], acc[mi][ni]);
        __builtin_amdgcn_s_setprio(0);
        __builtin_amdgcn_s_barrier();

        // ---- P1 (TR): read B_R(4); MFMA mt0-3 x nt2-3 (A_top held)
        bfr[0][0] = LDB(2, 0); bfr[0][1] = LDB(2, 1);
        bfr[1][0] = LDB(3, 0); bfr[1][1] = LDB(3, 1);
        __builtin_amdgcn_s_barrier();
        asm volatile("s_waitcnt lgkmcnt(0)" ::: "memory");
        __builtin_amdgcn_s_setprio(1);
        #pragma unroll
        for (int mi = 0; mi < 4; ++mi)
            #pragma unroll
            for (int ni = 0; ni < 2; ++ni)
                #pragma unroll
                for (int ks = 0; ks < 2; ++ks)
                    acc[mi][ni + 2] = MFMA16(af[mi][ks], bfr[ni][ks], acc[mi][ni + 2]);
        __builtin_amdgcn_s_setprio(0);
        __builtin_amdgcn_s_barrier();

        // ---- P2 (BR): read A_bot(8); stage t+2 A_top (A_top LDS freed after P1);
        //      MFMA mt4-7 x nt2-3 (B_R held)
        #pragma unroll
        for (int mi = 0; mi < 4; ++mi) { af[mi][0] = LDA(mi + 4, 0); af[mi][1] = LDA(mi + 4, 1); }
        if (pre) { gload16(A + srcA[0] + ko, Pb + ldsA[0]);
                   gload16(A + srcA[1] + ko, Pb + ldsA[1]); }
        __builtin_amdgcn_s_barrier();
        asm volatile("s_waitcnt lgkmcnt(0)" ::: "memory");
        __builtin_amdgcn_s_setprio(1);
        #pragma unroll
        for (int mi = 0; mi < 4; ++mi)
            #pragma unroll
            for (int ni = 0; ni < 2; ++ni)
                #pragma unroll
                for (int ks = 0; ks < 2; ++ks)
                    acc[mi + 4][ni + 2] = MFMA16(af[mi][ks], bfr[ni][ks], acc[mi + 4][ni + 2]);
        __builtin_amdgcn_s_setprio(0);
        __builtin_amdgcn_s_barrier();

        // ---- P3 (BL): re-read B_L(4); stage t+2 A_bot (A_bot LDS freed after P2);
        //      MFMA mt4-7 x nt0-1 (A_bot held)
        bfr[0][0] = LDB(0, 0); bfr[0][1] = LDB(0, 1);
        bfr[1][0] = LDB(1, 0); bfr[1][1] = LDB(1, 1);
        if (pre) { gload16(A + srcA[2] + ko, Pb + ldsA[2]);
                   gload16(A + srcA[3] + ko, Pb + ldsA[3]); }
        __builtin_amdgcn_s_barrier();
        asm volatile("s_waitcnt lgkmcnt(0)" ::: "memory");
        __builtin_amdgcn_s_setprio(1);
        #pragma unroll
        for (int mi = 0; mi < 4; ++mi)
            #pragma unroll
            for (int ni = 0; ni < 2; ++ni)
                #pragma unroll
                for (int ks = 0; ks < 2; ++ks)
                    acc[mi + 4][ni] = MFMA16(af[mi][ks], bfr[ni][ks], acc[mi + 4][ni]);
        __builtin_amdgcn_s_setprio(0);
        __builtin_amdgcn_s_barrier();

        // ---- tile end: B region fully consumed; stage t+2's B; counted wait
        if (pre) {
            #pragma unroll
            for (int j = 0; j < 4; ++j)
                gload16(Bt + srcB[j] + ko, Pb + ldsB[j]);
            asm volatile("s_waitcnt vmcnt(8)" ::: "memory");
        } else {
            asm volatile("s_waitcnt vmcnt(0)" ::: "memory");
        }
        __builtin_amdgcn_s_barrier();
    }
    #undef LDA
    #undef LDB

    // epilogue: region 0=Q, 1=K (block-uniform); C/D col = lane&15, row = 4*(lane>>4)+reg
    const int region = n0 >> 11;
    const float* bp = region ? bk : bq;
    unsigned short* outp = region ? Kb : Qb;
    #pragma unroll
    for (int mt = 0; mt < 8; ++mt) {
        #pragma unroll
        for (int nt = 0; nt < 4; ++nt) {
            int col = n0 + wc * 64 + nt * 16 + r;
            int lcol = col & 2047;
            float bvv = bp[lcol];
            f32x4 a = acc[mt][nt];
            int mrow = m0 + wr * 128 + mt * 16 + g * 4;
            #pragma unroll
            for (int q = 0; q < 4; ++q)
                outp[(size_t)(mrow + q) * 2048 + lcol] = f2bf(a[q] + bvv);
        }
    }
}

// ---------------- 2-phase GEMM (round-9 validated): V and O ----------------
template<int MODE>
__global__ __launch_bounds__(512, 2) void gemm8_bf16(
    const unsigned short* __restrict__ A,
    const unsigned short* __restrict__ Bt,
    const float* __restrict__ bias,
    void* __restrict__ Cout,
    int M, int N, int K)
{
    __shared__ __align__(16) unsigned char sm[147456];
    const int tid = threadIdx.x;
    const int wv = tid >> 6, ln = tid & 63;
    const int g = ln >> 4, r = ln & 15;
    const int wr = wv >> 2, wc = wv & 3;

    const int bid = blockIdx.x;
    const int lb = (bid & 7) * 32 + (bid >> 3);
    const int m0 = (lb & 31) * 128;
    const int n0 = (lb >> 5) * 256;

    unsigned srcA[2]; int ldsA[2];
    #pragma unroll
    for (int j = 0; j < 2; ++j) {
        int o = j * 8192 + tid * 16;
        int row = o >> 7;
        int lg = ((o >> 4) & 7) ^ (row & 7);
        srcA[j] = (unsigned)(m0 + row) * K + lg * 8;
        ldsA[j] = o;
    }
    unsigned srcB[4]; int ldsB[4];
    #pragma unroll
    for (int j = 0; j < 4; ++j) {
        int o = j * 8192 + tid * 16;
        int row = o >> 7;
        int lg = ((o >> 4) & 7) ^ (row & 7);
        srcB[j] = (unsigned)(n0 + row) * K + lg * 8;
        ldsB[j] = 16384 + o;
    }

    f32x4 acc[4][4];
    #pragma unroll
    for (int i = 0; i < 4; ++i)
        #pragma unroll
        for (int j = 0; j < 4; ++j)
            acc[i][j] = (f32x4){0.f, 0.f, 0.f, 0.f};

    const int NT = K >> 6;   // 32

    {
        unsigned char* b0 = sm;
        unsigned char* b1 = sm + 49152;
        #pragma unroll
        for (int j = 0; j < 2; ++j) gload16(A + srcA[j], b0 + ldsA[j]);
        #pragma unroll
        for (int j = 0; j < 4; ++j) gload16(Bt + srcB[j], b0 + ldsB[j]);
        #pragma unroll
        for (int j = 0; j < 2; ++j) gload16(A + srcA[j] + 64, b1 + ldsA[j]);
        #pragma unroll
        for (int j = 0; j < 4; ++j) gload16(Bt + srcB[j] + 64, b1 + ldsB[j]);
    }
    asm volatile("s_waitcnt vmcnt(6)" ::: "memory");
    __builtin_amdgcn_s_barrier();

    #define LDA(mi, ks) (*(const bf16x8*)(Ab + (wr * 64 + (mi) * 16 + r) * 128 + \
                         ((((ks) << 2) + g) ^ ((wr * 64 + (mi) * 16 + r) & 7)) * 16))
    #define LDB(ni, ks) (*(const bf16x8*)(Bb + (wc * 64 + (ni) * 16 + r) * 128 + \
                         ((((ks) << 2) + g) ^ ((wc * 64 + (ni) * 16 + r) & 7)) * 16))

    int csel = 0, psel = 2;
    for (int t = 0; t < NT; ++t) {
        const unsigned char* Ab = sm + csel * 49152;
        const unsigned char* Bb = Ab + 16384;
        unsigned char* Pb = sm + psel * 49152;
        const bool pre = (t + 2 < NT);
        const int ko = (t + 2) * 64;

        bf16x8 af[2][2], bfr[4][2];

        af[0][0] = LDA(0, 0); af[0][1] = LDA(0, 1);
        af[1][0] = LDA(1, 0); af[1][1] = LDA(1, 1);
        #pragma unroll
        for (int ni = 0; ni < 4; ++ni) { bfr[ni][0] = LDB(ni, 0); bfr[ni][1] = LDB(ni, 1); }
        if (pre) { gload16(Bt + srcB[0] + ko, Pb + ldsB[0]);
                   gload16(Bt + srcB[1] + ko, Pb + ldsB[1]);
                   gload16(Bt + srcB[2] + ko, Pb + ldsB[2]); }
        __builtin_amdgcn_s_barrier();
        asm volatile("s_waitcnt lgkmcnt(0)" ::: "memory");
        __builtin_amdgcn_s_setprio(1);
        #pragma unroll
        for (int mi = 0; mi < 2; ++mi)
            #pragma unroll
            for (int ni = 0; ni < 4; ++ni)
                #pragma unroll
                for (int ks = 0; ks < 2; ++ks)
                    acc[mi][ni] = MFMA16(af[mi][ks], bfr[ni][ks], acc[mi][ni]);
        __builtin_amdgcn_s_setprio(0);
        __builtin_amdgcn_s_barrier();

        af[0][0] = LDA(2, 0); af[0][1] = LDA(2, 1);
        af[1][0] = LDA(3, 0); af[1][1] = LDA(3, 1);
        if (pre) { gload16(Bt + srcB[3] + ko, Pb + ldsB[3]);
                   gload16(A + srcA[0] + ko, Pb + ldsA[0]);
                   gload16(A + srcA[1] + ko, Pb + ldsA[1]); }
        __builtin_amdgcn_s_barrier();
        asm volatile("s_waitcnt lgkmcnt(0)" ::: "memory");
        __builtin_amdgcn_s_setprio(1);
        #pragma unroll
        for (int mi = 0; mi < 2; ++mi)
            #pragma unroll
            for (int ni = 0; ni < 4; ++ni)
                #pragma unroll
                for (int ks = 0; ks < 2; ++ks)
                    acc[mi + 2][ni] = MFMA16(af[mi][ks], bfr[ni][ks], acc[mi + 2][ni]);
        __builtin_amdgcn_s_setprio(0);

        if (pre) asm volatile("s_waitcnt vmcnt(6)" ::: "memory");
        else     asm volatile("s_waitcnt vmcnt(0)" ::: "memory");
        __builtin_amdgcn_s_barrier();

        csel = (csel == 2) ? 0 : csel + 1;
        psel = (psel == 2) ? 0 : psel + 1;
    }
    #undef LDA
    #undef LDB

    #pragma unroll
    for (int mt = 0; mt < 4; ++mt) {
        #pragma unroll
        for (int nt = 0; nt < 4; ++nt) {
            int col = n0 + wc * 64 + nt * 16 + r;
            float bvv = bias[col];
            f32x4 a = acc[mt][nt];
            int mrow = m0 + wr * 64 + mt * 16 + g * 4;
            if (MODE == 0) {
                #pragma unroll
                for (int q = 0; q < 4; ++q)
                    ((unsigned short*)Cout)[(size_t)(mrow + q) * N + col] = f2bf(a[q] + bvv);
            } else if (MODE == 2) {
                #pragma unroll
                for (int q = 0; q < 4; ++q)
                    ((float*)Cout)[(size_t)(mrow + q) * N + col] = a[q] + bvv;
            } else {
                int b = mrow >> 11, s0x = mrow & 2047;
                ushort4 o;
                o.x = f2bf(a[0] + bvv); o.y = f2bf(a[1] + bvv);
                o.z = f2bf(a[2] + bvv); o.w = f2bf(a[3] + bvv);
                *(ushort4*)((unsigned short*)Cout + ((size_t)(b * 2048 + col)) * 2048 + s0x) = o;
            }
        }
    }
}

// ---------------- flash attention: KVBLK=64, 2-buf counted pipeline, mask in LDS ----------------
// Round-10 validated (104 µs, VGPR 104).
__global__ __launch_bounds__(256, 2) void attn_fwd(
    const unsigned short* __restrict__ Q,
    const unsigned short* __restrict__ K,
    const unsigned short* __restrict__ V,
    const float* __restrict__ maskl2,   // mask * log2(e)
    unsigned short* __restrict__ O)
{
    __shared__ __align__(16) unsigned char sm[73728]; // 2 x 32KB KV bufs + 8KB mask @65536
    const int tid = threadIdx.x, wv = tid >> 6, ln = tid & 63;
    const int hi = ln >> 5, qr = ln & 31;

    const int bid = blockIdx.x;
    const int lb = (bid & 7) * 64 + (bid >> 3);
    const int qb = lb & 15;
    const int bh = lb >> 4;
    const int h = bh & 15, b = bh >> 4;

    const size_t rowQ0 = (size_t)(b * 2048 + qb * 128 + wv * 32);
    const float SCL2 = 0.08838834764831845f * 1.4426950408889634f; // scale*log2e

    unsigned srcK[4], srcV[4];
    int ldsK[4], ldsV[4];
    #pragma unroll
    for (int i = 0; i < 4; ++i) {
        int ch = wv * 4 + i;
        int o = ch * 1024 + ln * 16;
        { int row = o >> 8; int gl = ((o >> 4) & 15) ^ (row & 7);
          srcK[i] = (unsigned)((b * 2048 + row) * 2048 + h * 128 + gl * 8);
          ldsK[i] = o; }
        { int d = o >> 7; int gl = ((o >> 4) & 7) ^ (d & 7);
          srcV[i] = (unsigned)((b * 2048 + h * 128 + d) * 2048 + gl * 8);
          ldsV[i] = 16384 + o; }
    }

    #define STAGE(t, base) { \
        _Pragma("unroll") \
        for (int i = 0; i < 4; ++i) { \
            gload16(K + srcK[i] + (unsigned)(t) * (64u * 2048u), sm + (base) + ldsK[i]); \
            gload16(V + srcV[i] + (unsigned)(t) * 64u, sm + (base) + ldsV[i]); \
        } }

    #pragma unroll
    for (int i = 0; i < 2; ++i)
        gload16(maskl2 + b * 2048 + wv * 512 + i * 256 + ln * 4,
                sm + 65536 + wv * 2048 + i * 1024);
    STAGE(0, 0); STAGE(1, 32768);

    bf16x8 qf[8];
    #pragma unroll
    for (int ks = 0; ks < 8; ++ks)
        qf[ks] = *(const bf16x8*)(Q + (rowQ0 + qr) * 2048 + h * 128 + ks * 16 + hi * 8);

    f32x16 acc[4];
    #pragma unroll
    for (int i = 0; i < 4; ++i)
        #pragma unroll
        for (int j = 0; j < 16; ++j)
            acc[i][j] = 0.f;
    float mr = -3.0e38f, lr = 0.f;

    const float* ml = (const float*)(sm + 65536);

    asm volatile("s_waitcnt vmcnt(8)" ::: "memory");
    __builtin_amdgcn_s_barrier();

    for (int t = 0; t < 32; ++t) {
        const unsigned char* Kt = sm + (t & 1) * 32768;
        const unsigned char* Vt = Kt + 16384;

        f32x4 mk[2][4];
        #pragma unroll
        for (int kb2 = 0; kb2 < 2; ++kb2)
            #pragma unroll
            for (int rg = 0; rg < 4; ++rg)
                mk[kb2][rg] = *(const f32x4*)(ml + t * 64 + kb2 * 32 + rg * 8 + hi * 4);

        f32x16 sf0, sf1;
        #pragma unroll
        for (int j = 0; j < 16; ++j) { sf0[j] = 0.f; sf1[j] = 0.f; }
        __builtin_amdgcn_s_setprio(1);
        #pragma unroll
        for (int ks = 0; ks < 8; ++ks) {
            int row0 = qr, row1 = 32 + qr;
            int s0 = ((2 * ks + hi) ^ (row0 & 7));
            int s1 = ((2 * ks + hi) ^ (row1 & 7));
            bf16x8 kf0 = *(const bf16x8*)(Kt + row0 * 256 + s0 * 16);
            bf16x8 kf1 = *(const bf16x8*)(Kt + row1 * 256 + s1 * 16);
            sf0 = MFMA32(kf0, qf[ks], sf0);
            sf1 = MFMA32(kf1, qf[ks], sf1);
        }
        __builtin_amdgcn_s_setprio(0);

        float sv[2][16];
        #pragma unroll
        for (int reg = 0; reg < 16; ++reg) {
            sv[0][reg] = sf0[reg] * SCL2 + mk[0][reg >> 2][reg & 3];
            sv[1][reg] = sf1[reg] * SCL2 + mk[1][reg >> 2][reg & 3];
        }

        float mx[8];
        #pragma unroll
        for (int j = 0; j < 8; ++j)
            mx[j] = fmaxf(fmaxf(sv[0][2*j], sv[0][2*j+1]),
                          fmaxf(sv[1][2*j], sv[1][2*j+1]));
        float m01 = fmaxf(fmaxf(fmaxf(mx[0], mx[1]), fmaxf(mx[2], mx[3])),
                          fmaxf(fmaxf(mx[4], mx[5]), fmaxf(mx[6], mx[7])));
        float2 mp = xswap(m01);
        float mt = fmaxf(mp.x, mp.y);

        float alpha = 1.f;
        int allskip = __all(mt <= mr + 8.f);
        if (!allskip) {
            float nm = fmaxf(mr, mt);
            alpha = __builtin_amdgcn_exp2f(mr - nm);
            mr = nm;
            #pragma unroll
            for (int dblk = 0; dblk < 4; ++dblk)
                #pragma unroll
                for (int reg = 0; reg < 16; ++reg)
                    acc[dblk][reg] *= alpha;
        }

        float s0 = 0.f, s1 = 0.f, s2 = 0.f, s3 = 0.f;
        #pragma unroll
        for (int kb2 = 0; kb2 < 2; ++kb2)
            #pragma unroll
            for (int reg = 0; reg < 16; reg += 4) {
                float p0 = __builtin_amdgcn_exp2f(sv[kb2][reg + 0] - mr);
                float p1 = __builtin_amdgcn_exp2f(sv[kb2][reg + 1] - mr);
                float p2 = __builtin_amdgcn_exp2f(sv[kb2][reg + 2] - mr);
                float p3 = __builtin_amdgcn_exp2f(sv[kb2][reg + 3] - mr);
                sv[kb2][reg + 0] = p0; sv[kb2][reg + 1] = p1;
                sv[kb2][reg + 2] = p2; sv[kb2][reg + 3] = p3;
                s0 += p0; s1 += p1; s2 += p2; s3 += p3;
            }
        float rsl = (s0 + s1) + (s2 + s3);
        float2 rp = xswap(rsl);
        float rs = rp.x + rp.y;
        lr = lr * alpha + rs;

        bf16x8 pfr[4];
        #pragma unroll
        for (int kb16 = 0; kb16 < 4; ++kb16) {
            const int kb2 = kb16 >> 1, i2 = kb16 & 1;
            float* pv = sv[kb2];
            unsigned W00 = packbf(pv[(2*i2+0)*4 + 0], pv[(2*i2+0)*4 + 1]);
            unsigned W01 = packbf(pv[(2*i2+0)*4 + 2], pv[(2*i2+0)*4 + 3]);
            unsigned W10 = packbf(pv[(2*i2+1)*4 + 0], pv[(2*i2+1)*4 + 1]);
            unsigned W11 = packbf(pv[(2*i2+1)*4 + 2], pv[(2*i2+1)*4 + 3]);
            pswap(W00, W10);
            pswap(W01, W11);
            union { unsigned w[4]; bf16x8 v; } u;
            u.w[0] = W00; u.w[1] = W01; u.w[2] = W10; u.w[3] = W11;
            pfr[kb16] = u.v;
        }

        __builtin_amdgcn_s_setprio(1);
        #pragma unroll
        for (int dblk = 0; dblk < 4; ++dblk) {
            int d = dblk * 32 + qr;
            f32x16 a = acc[dblk];
            #pragma unroll
            for (int kb16 = 0; kb16 < 4; ++kb16) {
                int s = ((2 * kb16 + hi) ^ (d & 7));
                bf16x8 vf = *(const bf16x8*)(Vt + d * 128 + s * 16);
                a = MFMA32(vf, pfr[kb16], a);
            }
            acc[dblk] = a;
        }
        __builtin_amdgcn_s_setprio(0);

        __builtin_amdgcn_s_barrier();
        if (t + 2 < 32) {
            STAGE(t + 2, (t & 1) * 32768);
            asm volatile("s_waitcnt vmcnt(8)" ::: "memory");
        } else {
            asm volatile("s_waitcnt vmcnt(0)" ::: "memory");
        }
        __builtin_amdgcn_s_barrier();
    }

    float linv = 1.f / lr;
    unsigned short* orow = O + (rowQ0 + qr) * 2048 + h * 128;
    #pragma unroll
    for (int dblk = 0; dblk < 4; ++dblk)
        #pragma unroll
        for (int rg = 0; rg < 4; ++rg) {
            float v0 = acc[dblk][rg * 4 + 0] * linv;
            float v1 = acc[dblk][rg * 4 + 1] * linv;
            float v2 = acc[dblk][rg * 4 + 2] * linv;
            float v3 = acc[dblk][rg * 4 + 3] * linv;
            uint2 o;
            o.x = packbf(v0, v1);
            o.y = packbf(v2, v3);
            *(uint2*)(orow + dblk * 32 + rg * 8 + hi * 4) = o;
        }
    #undef STAGE
}

// ---------------- host launch ----------------
extern "C" void kernel_launch(void* const* d_in, const int* in_sizes, int n_in,
                              void* d_out, int out_size, void* d_ws, size_t ws_size,
                              hipStream_t stream)
{
    (void)in_sizes; (void)n_in; (void)out_size; (void)ws_size;
    const float* x    = (const float*)d_in[0];
    const float* mask = (const float*)d_in[1];
    const float* Wq   = (const float*)d_in[2];
    const float* bq   = (const float*)d_in[3];
    const float* Wk   = (const float*)d_in[4];
    const float* bk   = (const float*)d_in[5];
    const float* Wv   = (const float*)d_in[6];
    const float* bv   = (const float*)d_in[7];
    const float* Wo   = (const float*)d_in[8];
    const float* bo   = (const float*)d_in[9];
    float* out = (float*)d_out;

    char* ws = (char*)d_ws;
    unsigned short* xb  = (unsigned short*)(ws);
    unsigned short* Wqt = (unsigned short*)(ws + (16u << 20));   // Wqt|Wkt contiguous (QK B)
    unsigned short* Wvt = (unsigned short*)(ws + (32u << 20));
    unsigned short* Wot = (unsigned short*)(ws + (40u << 20));
    unsigned short* Qb  = (unsigned short*)(ws + (48u << 20));
    unsigned short* Kb  = (unsigned short*)(ws + (64u << 20));
    unsigned short* Vtb = (unsigned short*)(ws + (80u << 20));
    unsigned short* Ab  = (unsigned short*)(ws + (16u << 20));   // dead Wqt/Wkt after attn input built
    float*          mkl = out;                                   // scratch in d_out until gemmO

    cast_f32_bf16<<<2052, 256, 0, stream>>>(x, xb, mask, mkl);
    transpose_cast4<<<dim3(64, 64, 4), dim3(32, 8), 0, stream>>>(Wq, Wk, Wv, Wo, Wqt);

    gemmQK<<<256, 512, 0, stream>>>(xb, Wqt, bq, bk, Qb, Kb);
    gemm8_bf16<1><<<256, 512, 0, stream>>>(xb, Wvt, bv, Vtb, MTOT, HHH, HHH);

    attn_fwd<<<512, 256, 0, stream>>>(Qb, Kb, Vtb, mkl, Ab);

    gemm8_bf16<2><<<256, 512, 0, stream>>>(Ab, Wot, bo, out, MTOT, HHH, HHH);
}

// Round 18
// 257.501 us; speedup vs baseline: 2.2825x; 1.0227x over previous
//
#include <hip/hip_runtime.h>
#include <hip/hip_bf16.h>
#include <stdint.h>

// Problem constants
#define BB   2
#define SS   2048
#define HHH  2048
#define NHH  16
#define HDD  128
#define MTOT 4096   // BB*SS

typedef __bf16 bf16x8 __attribute__((ext_vector_type(8)));
typedef float  f32x4  __attribute__((ext_vector_type(4)));
typedef float  f32x16 __attribute__((ext_vector_type(16)));

#define MFMA16(a, b, c) __builtin_amdgcn_mfma_f32_16x16x32_bf16((a), (b), (c), 0, 0, 0)
#define MFMA32(a, b, c) __builtin_amdgcn_mfma_f32_32x32x16_bf16((a), (b), (c), 0, 0, 0)

__device__ __forceinline__ unsigned short f2bf(float f) {
    union { float f; unsigned u; } v; v.f = f;
    unsigned r = v.u + 0x7FFFu + ((v.u >> 16) & 1u);   // RNE
    return (unsigned short)(r >> 16);
}

__device__ __forceinline__ unsigned packbf(float a, float b) {
    union { __bf16 h[2]; unsigned u; } p;
    p.h[0] = (__bf16)a; p.h[1] = (__bf16)b;
    return p.u;
}

// v_permlane32_swap_b32: a' = [a.lo32, b.lo32], b' = [a.hi32, b.hi32]
__device__ __forceinline__ void pswap(unsigned &a, unsigned &b) {
    asm("v_permlane32_swap_b32 %0, %1" : "+v"(a), "+v"(b));
}

// cross-half (lane ^ 32) pair: returns {own-half view, other-half view}
__device__ __forceinline__ float2 xswap(float x) {
    unsigned a = __builtin_bit_cast(unsigned, x);
    unsigned b;
    asm("v_mov_b32 %0, %1" : "=v"(b) : "v"(a));   // force distinct register
    asm("v_permlane32_swap_b32 %0, %1" : "+v"(a), "+v"(b));
    return make_float2(__builtin_bit_cast(float, a), __builtin_bit_cast(float, b));
}

// async global->LDS, 16B per lane. LDS dest is wave-uniform base + lane*16.
__device__ __forceinline__ void gload16(const void* src, void* lds) {
    __builtin_amdgcn_global_load_lds(
        (__attribute__((address_space(1))) void*)src,
        (__attribute__((address_space(3))) void*)lds,
        16, 0, 0);
}

// ---------- merged prep: weight transpose+cast (blocks 0..16383),
//            mask pre-scale (16384..18435 upper 4), x cast (16384..18431) ----------
__global__ void prep_all(const float* __restrict__ x, unsigned short* __restrict__ xb,
                         const float* __restrict__ mask, float* __restrict__ mkl,
                         const float* __restrict__ W0, const float* __restrict__ W1,
                         const float* __restrict__ W2, const float* __restrict__ W3,
                         unsigned short* __restrict__ Wt) {
    __shared__ float tile[32][33];
    int bid = blockIdx.x;
    if (bid < 16384) {
        int z = bid >> 12, rem = bid & 4095;
        int bx = rem & 63, by = rem >> 6;
        const float* in = z == 0 ? W0 : z == 1 ? W1 : z == 2 ? W2 : W3;
        unsigned short* o = Wt + (size_t)z * ((size_t)HHH * HHH);
        int c0 = bx * 32, r0 = by * 32;
        int tx = threadIdx.x & 31, ty = threadIdx.x >> 5;
        #pragma unroll
        for (int i = 0; i < 32; i += 8)
            tile[ty + i][tx] = in[(size_t)(r0 + ty + i) * HHH + c0 + tx];
        __syncthreads();
        #pragma unroll
        for (int i = 0; i < 32; i += 8)
            o[(size_t)(c0 + ty + i) * HHH + r0 + tx] = f2bf(tile[tx][ty + i]);
        return;
    }
    bid -= 16384;
    if (bid >= 2048) {
        int i = (bid - 2048) * 256 + threadIdx.x;   // 4 blocks cover BB*SS
        mkl[i] = mask[i] * 1.4426950408889634f;
        return;
    }
    const int n = MTOT * HHH;
    const int stride = 2048 * 256 * 4;
    for (int i = (bid * 256 + threadIdx.x) * 4; i < n; i += stride) {
        float4 v = *(const float4*)(x + i);
        ushort4 o;
        o.x = f2bf(v.x); o.y = f2bf(v.y); o.z = f2bf(v.z); o.w = f2bf(v.w);
        *(ushort4*)(xb + i) = o;
    }
}

// ---------------- fused QK GEMM, 256x256 tile, 4-phase interleave ----------------
// Round-17 validated. XCD mapping: 4m x 8n per XCD -> A panel (4MB) L2-resident;
// bijective: x=((mp>>2)<<1)|(np>>3), j=(mp&3)|((np&7)<<2).
__global__ __launch_bounds__(512, 2) void gemmQK(
    const unsigned short* __restrict__ A,
    const unsigned short* __restrict__ Bt,     // Wqt|Wkt contiguous, 4096 x 2048
    const float* __restrict__ bq,
    const float* __restrict__ bk,
    unsigned short* __restrict__ Qb,
    unsigned short* __restrict__ Kb)
{
    __shared__ __align__(16) unsigned char sm[131072];
    const int tid = threadIdx.x;
    const int wv = tid >> 6, ln = tid & 63;
    const int g = ln >> 4, r = ln & 15;
    const int wr = wv >> 2, wc = wv & 3;
    const int K = HHH;

    const int bid = blockIdx.x;
    const int xc = bid & 7, j = bid >> 3;
    const int m0 = ((xc >> 1) * 4 + (j & 3)) * 256;
    const int n0 = ((xc & 1) * 8 + (j >> 2)) * 256;

    unsigned srcA[4], srcB[4];
    int ldsA[4], ldsB[4];
    #pragma unroll
    for (int jj = 0; jj < 4; ++jj) {
        int o = jj * 8192 + tid * 16;
        int row = o >> 7;
        int lg = ((o >> 4) & 7) ^ (row & 7);
        srcA[jj] = (unsigned)(m0 + row) * K + lg * 8;
        srcB[jj] = (unsigned)(n0 + row) * K + lg * 8;
        ldsA[jj] = o;
        ldsB[jj] = 32768 + o;
    }

    f32x4 acc[8][4];
    #pragma unroll
    for (int i = 0; i < 8; ++i)
        #pragma unroll
        for (int jj = 0; jj < 4; ++jj)
            acc[i][jj] = (f32x4){0.f, 0.f, 0.f, 0.f};

    #pragma unroll
    for (int jj = 0; jj < 4; ++jj) { gload16(A + srcA[jj], sm + ldsA[jj]);
                                     gload16(Bt + srcB[jj], sm + ldsB[jj]); }
    #pragma unroll
    for (int jj = 0; jj < 4; ++jj) { gload16(A + srcA[jj] + 64, sm + 65536 + ldsA[jj]);
                                     gload16(Bt + srcB[jj] + 64, sm + 65536 + ldsB[jj]); }
    asm volatile("s_waitcnt vmcnt(8)" ::: "memory");
    __builtin_amdgcn_s_barrier();

    #define LDA(mi, ks) (*(const bf16x8*)(Ab + (wr * 128 + (mi) * 16 + r) * 128 + \
                         ((((ks) << 2) + g) ^ ((wr * 128 + (mi) * 16 + r) & 7)) * 16))
    #define LDB(ni, ks) (*(const bf16x8*)(Bb + (wc * 64 + (ni) * 16 + r) * 128 + \
                         ((((ks) << 2) + g) ^ ((wc * 64 + (ni) * 16 + r) & 7)) * 16))

    for (int t = 0; t < 32; ++t) {
        const int base = (t & 1) * 65536;
        const unsigned char* Ab = sm + base;
        const unsigned char* Bb = Ab + 32768;
        unsigned char* Pb = sm + base;
        const bool pre = (t + 2 < 32);
        const int ko = (t + 2) * 64;

        bf16x8 af[4][2], bfr[2][2];

        // ---- P0 (TL)
        #pragma unroll
        for (int mi = 0; mi < 4; ++mi) { af[mi][0] = LDA(mi, 0); af[mi][1] = LDA(mi, 1); }
        bfr[0][0] = LDB(0, 0); bfr[0][1] = LDB(0, 1);
        bfr[1][0] = LDB(1, 0); bfr[1][1] = LDB(1, 1);
        __builtin_amdgcn_s_barrier();
        asm volatile("s_waitcnt lgkmcnt(0)" ::: "memory");
        __builtin_amdgcn_s_setprio(1);
        #pragma unroll
        for (int mi = 0; mi < 4; ++mi)
            #pragma unroll
            for (int ni = 0; ni < 2; ++ni)
                #pragma unroll
                for (int ks = 0; ks < 2; ++ks)
                    acc[mi][ni] = MFMA16(af[mi][ks], bfr[ni][ks], acc[mi][ni]);
        __builtin_amdgcn_s_setprio(0);
        __builtin_amdgcn_s_barrier();

        // ---- P1 (TR)
        bfr[0][0] = LDB(2, 0); bfr[0][1] = LDB(2, 1);
        bfr[1][0] = LDB(3, 0); bfr[1][1] = LDB(3, 1);
        __builtin_amdgcn_s_barrier();
        asm volatile("s_waitcnt lgkmcnt(0)" ::: "memory");
        __builtin_amdgcn_s_setprio(1);
        #pragma unroll
        for (int mi = 0; mi < 4; ++mi)
            #pragma unroll
            for (int ni = 0; ni < 2; ++ni)
                #pragma unroll
                for (int ks = 0; ks < 2; ++ks)
                    acc[mi][ni + 2] = MFMA16(af[mi][ks], bfr[ni][ks], acc[mi][ni + 2]);
        __builtin_amdgcn_s_setprio(0);
        __builtin_amdgcn_s_barrier();

        // ---- P2 (BR): stage t+2 A_top
        #pragma unroll
        for (int mi = 0; mi < 4; ++mi) { af[mi][0] = LDA(mi + 4, 0); af[mi][1] = LDA(mi + 4, 1); }
        if (pre) { gload16(A + srcA[0] + ko, Pb + ldsA[0]);
                   gload16(A + srcA[1] + ko, Pb + ldsA[1]); }
        __builtin_amdgcn_s_barrier();
        asm volatile("s_waitcnt lgkmcnt(0)" ::: "memory");
        __builtin_amdgcn_s_setprio(1);
        #pragma unroll
        for (int mi = 0; mi < 4; ++mi)
            #pragma unroll
            for (int ni = 0; ni < 2; ++ni)
                #pragma unroll
                for (int ks = 0; ks < 2; ++ks)
                    acc[mi + 4][ni + 2] = MFMA16(af[mi][ks], bfr[ni][ks], acc[mi + 4][ni + 2]);
        __builtin_amdgcn_s_setprio(0);
        __builtin_amdgcn_s_barrier();

        // ---- P3 (BL): stage t+2 A_bot
        bfr[0][0] = LDB(0, 0); bfr[0][1] = LDB(0, 1);
        bfr[1][0] = LDB(1, 0); bfr[1][1] = LDB(1, 1);
        if (pre) { gload16(A + srcA[2] + ko, Pb + ldsA[2]);
                   gload16(A + srcA[3] + ko, Pb + ldsA[3]); }
        __builtin_amdgcn_s_barrier();
        asm volatile("s_waitcnt lgkmcnt(0)" ::: "memory");
        __builtin_amdgcn_s_setprio(1);
        #pragma unroll
        for (int mi = 0; mi < 4; ++mi)
            #pragma unroll
            for (int ni = 0; ni < 2; ++ni)
                #pragma unroll
                for (int ks = 0; ks < 2; ++ks)
                    acc[mi + 4][ni] = MFMA16(af[mi][ks], bfr[ni][ks], acc[mi + 4][ni]);
        __builtin_amdgcn_s_setprio(0);
        __builtin_amdgcn_s_barrier();

        // ---- tile end: stage t+2 B; counted wait
        if (pre) {
            #pragma unroll
            for (int jj = 0; jj < 4; ++jj)
                gload16(Bt + srcB[jj] + ko, Pb + ldsB[jj]);
            asm volatile("s_waitcnt vmcnt(8)" ::: "memory");
        } else {
            asm volatile("s_waitcnt vmcnt(0)" ::: "memory");
        }
        __builtin_amdgcn_s_barrier();
    }
    #undef LDA
    #undef LDB

    const int region = n0 >> 11;
    const float* bp = region ? bk : bq;
    unsigned short* outp = region ? Kb : Qb;
    #pragma unroll
    for (int mt = 0; mt < 8; ++mt) {
        #pragma unroll
        for (int nt = 0; nt < 4; ++nt) {
            int col = n0 + wc * 64 + nt * 16 + r;
            int lcol = col & 2047;
            float bvv = bp[lcol];
            f32x4 a = acc[mt][nt];
            int mrow = m0 + wr * 128 + mt * 16 + g * 4;
            #pragma unroll
            for (int q = 0; q < 4; ++q)
                outp[(size_t)(mrow + q) * 2048 + lcol] = f2bf(a[q] + bvv);
        }
    }
}

// ---------------- 2-phase GEMM (round-9 validated): V and O ----------------
// XCD mapping: 8m x 4n per XCD; bijective: x=(mp>>3)|((np>>2)<<2), j=(mp&7)|((np&3)<<3).
template<int MODE>
__global__ __launch_bounds__(512, 2) void gemm8_bf16(
    const unsigned short* __restrict__ A,
    const unsigned short* __restrict__ Bt,
    const float* __restrict__ bias,
    void* __restrict__ Cout,
    int M, int N, int K)
{
    __shared__ __align__(16) unsigned char sm[147456];
    const int tid = threadIdx.x;
    const int wv = tid >> 6, ln = tid & 63;
    const int g = ln >> 4, r = ln & 15;
    const int wr = wv >> 2, wc = wv & 3;

    const int bid = blockIdx.x;
    const int xc = bid & 7, j = bid >> 3;
    const int m0 = ((xc & 3) * 8 + (j & 7)) * 128;
    const int n0 = ((xc >> 2) * 4 + (j >> 3)) * 256;

    unsigned srcA[2]; int ldsA[2];
    #pragma unroll
    for (int jj = 0; jj < 2; ++jj) {
        int o = jj * 8192 + tid * 16;
        int row = o >> 7;
        int lg = ((o >> 4) & 7) ^ (row & 7);
        srcA[jj] = (unsigned)(m0 + row) * K + lg * 8;
        ldsA[jj] = o;
    }
    unsigned srcB[4]; int ldsB[4];
    #pragma unroll
    for (int jj = 0; jj < 4; ++jj) {
        int o = jj * 8192 + tid * 16;
        int row = o >> 7;
        int lg = ((o >> 4) & 7) ^ (row & 7);
        srcB[jj] = (unsigned)(n0 + row) * K + lg * 8;
        ldsB[jj] = 16384 + o;
    }

    f32x4 acc[4][4];
    #pragma unroll
    for (int i = 0; i < 4; ++i)
        #pragma unroll
        for (int jj = 0; jj < 4; ++jj)
            acc[i][jj] = (f32x4){0.f, 0.f, 0.f, 0.f};

    const int NT = K >> 6;   // 32

    {
        unsigned char* b0 = sm;
        unsigned char* b1 = sm + 49152;
        #pragma unroll
        for (int jj = 0; jj < 2; ++jj) gload16(A + srcA[jj], b0 + ldsA[jj]);
        #pragma unroll
        for (int jj = 0; jj < 4; ++jj) gload16(Bt + srcB[jj], b0 + ldsB[jj]);
        #pragma unroll
        for (int jj = 0; jj < 2; ++jj) gload16(A + srcA[jj] + 64, b1 + ldsA[jj]);
        #pragma unroll
        for (int jj = 0; jj < 4; ++jj) gload16(Bt + srcB[jj] + 64, b1 + ldsB[jj]);
    }
    asm volatile("s_waitcnt vmcnt(6)" ::: "memory");
    __builtin_amdgcn_s_barrier();

    #define LDA(mi, ks) (*(const bf16x8*)(Ab + (wr * 64 + (mi) * 16 + r) * 128 + \
                         ((((ks) << 2) + g) ^ ((wr * 64 + (mi) * 16 + r) & 7)) * 16))
    #define LDB(ni, ks) (*(const bf16x8*)(Bb + (wc * 64 + (ni) * 16 + r) * 128 + \
                         ((((ks) << 2) + g) ^ ((wc * 64 + (ni) * 16 + r) & 7)) * 16))

    int csel = 0, psel = 2;
    for (int t = 0; t < NT; ++t) {
        const unsigned char* Ab = sm + csel * 49152;
        const unsigned char* Bb = Ab + 16384;
        unsigned char* Pb = sm + psel * 49152;
        const bool pre = (t + 2 < NT);
        const int ko = (t + 2) * 64;

        bf16x8 af[2][2], bfr[4][2];

        af[0][0] = LDA(0, 0); af[0][1] = LDA(0, 1);
        af[1][0] = LDA(1, 0); af[1][1] = LDA(1, 1);
        #pragma unroll
        for (int ni = 0; ni < 4; ++ni) { bfr[ni][0] = LDB(ni, 0); bfr[ni][1] = LDB(ni, 1); }
        if (pre) { gload16(Bt + srcB[0] + ko, Pb + ldsB[0]);
                   gload16(Bt + srcB[1] + ko, Pb + ldsB[1]);
                   gload16(Bt + srcB[2] + ko, Pb + ldsB[2]); }
        __builtin_amdgcn_s_barrier();
        asm volatile("s_waitcnt lgkmcnt(0)" ::: "memory");
        __builtin_amdgcn_s_setprio(1);
        #pragma unroll
        for (int mi = 0; mi < 2; ++mi)
            #pragma unroll
            for (int ni = 0; ni < 4; ++ni)
                #pragma unroll
                for (int ks = 0; ks < 2; ++ks)
                    acc[mi][ni] = MFMA16(af[mi][ks], bfr[ni][ks], acc[mi][ni]);
        __builtin_amdgcn_s_setprio(0);
        __builtin_amdgcn_s_barrier();

        af[0][0] = LDA(2, 0); af[0][1] = LDA(2, 1);
        af[1][0] = LDA(3, 0); af[1][1] = LDA(3, 1);
        if (pre) { gload16(Bt + srcB[3] + ko, Pb + ldsB[3]);
                   gload16(A + srcA[0] + ko, Pb + ldsA[0]);
                   gload16(A + srcA[1] + ko, Pb + ldsA[1]); }
        __builtin_amdgcn_s_barrier();
        asm volatile("s_waitcnt lgkmcnt(0)" ::: "memory");
        __builtin_amdgcn_s_setprio(1);
        #pragma unroll
        for (int mi = 0; mi < 2; ++mi)
            #pragma unroll
            for (int ni = 0; ni < 4; ++ni)
                #pragma unroll
                for (int ks = 0; ks < 2; ++ks)
                    acc[mi + 2][ni] = MFMA16(af[mi][ks], bfr[ni][ks], acc[mi + 2][ni]);
        __builtin_amdgcn_s_setprio(0);

        if (pre) asm volatile("s_waitcnt vmcnt(6)" ::: "memory");
        else     asm volatile("s_waitcnt vmcnt(0)" ::: "memory");
        __builtin_amdgcn_s_barrier();

        csel = (csel == 2) ? 0 : csel + 1;
        psel = (psel == 2) ? 0 : psel + 1;
    }
    #undef LDA
    #undef LDB

    #pragma unroll
    for (int mt = 0; mt < 4; ++mt) {
        #pragma unroll
        for (int nt = 0; nt < 4; ++nt) {
            int col = n0 + wc * 64 + nt * 16 + r;
            float bvv = bias[col];
            f32x4 a = acc[mt][nt];
            int mrow = m0 + wr * 64 + mt * 16 + g * 4;
            if (MODE == 0) {
                #pragma unroll
                for (int q = 0; q < 4; ++q)
                    ((unsigned short*)Cout)[(size_t)(mrow + q) * N + col] = f2bf(a[q] + bvv);
            } else if (MODE == 2) {
                #pragma unroll
                for (int q = 0; q < 4; ++q)
                    ((float*)Cout)[(size_t)(mrow + q) * N + col] = a[q] + bvv;
            } else {
                int b = mrow >> 11, s0x = mrow & 2047;
                ushort4 o;
                o.x = f2bf(a[0] + bvv); o.y = f2bf(a[1] + bvv);
                o.z = f2bf(a[2] + bvv); o.w = f2bf(a[3] + bvv);
                *(ushort4*)((unsigned short*)Cout + ((size_t)(b * 2048 + col)) * 2048 + s0x) = o;
            }
        }
    }
}

// ---------------- flash attention: KVBLK=64, 2-buf counted pipeline, mask in LDS ----------------
// Round-10 validated (104 µs, VGPR 104).
__global__ __launch_bounds__(256, 2) void attn_fwd(
    const unsigned short* __restrict__ Q,
    const unsigned short* __restrict__ K,
    const unsigned short* __restrict__ V,
    const float* __restrict__ maskl2,   // mask * log2(e)
    unsigned short* __restrict__ O)
{
    __shared__ __align__(16) unsigned char sm[73728]; // 2 x 32KB KV bufs + 8KB mask @65536
    const int tid = threadIdx.x, wv = tid >> 6, ln = tid & 63;
    const int hi = ln >> 5, qr = ln & 31;

    const int bid = blockIdx.x;
    const int lb = (bid & 7) * 64 + (bid >> 3);
    const int qb = lb & 15;
    const int bh = lb >> 4;
    const int h = bh & 15, b = bh >> 4;

    const size_t rowQ0 = (size_t)(b * 2048 + qb * 128 + wv * 32);
    const float SCL2 = 0.08838834764831845f * 1.4426950408889634f; // scale*log2e

    unsigned srcK[4], srcV[4];
    int ldsK[4], ldsV[4];
    #pragma unroll
    for (int i = 0; i < 4; ++i) {
        int ch = wv * 4 + i;
        int o = ch * 1024 + ln * 16;
        { int row = o >> 8; int gl = ((o >> 4) & 15) ^ (row & 7);
          srcK[i] = (unsigned)((b * 2048 + row) * 2048 + h * 128 + gl * 8);
          ldsK[i] = o; }
        { int d = o >> 7; int gl = ((o >> 4) & 7) ^ (d & 7);
          srcV[i] = (unsigned)((b * 2048 + h * 128 + d) * 2048 + gl * 8);
          ldsV[i] = 16384 + o; }
    }

    #define STAGE(t, base) { \
        _Pragma("unroll") \
        for (int i = 0; i < 4; ++i) { \
            gload16(K + srcK[i] + (unsigned)(t) * (64u * 2048u), sm + (base) + ldsK[i]); \
            gload16(V + srcV[i] + (unsigned)(t) * 64u, sm + (base) + ldsV[i]); \
        } }

    #pragma unroll
    for (int i = 0; i < 2; ++i)
        gload16(maskl2 + b * 2048 + wv * 512 + i * 256 + ln * 4,
                sm + 65536 + wv * 2048 + i * 1024);
    STAGE(0, 0); STAGE(1, 32768);

    bf16x8 qf[8];
    #pragma unroll
    for (int ks = 0; ks < 8; ++ks)
        qf[ks] = *(const bf16x8*)(Q + (rowQ0 + qr) * 2048 + h * 128 + ks * 16 + hi * 8);

    f32x16 acc[4];
    #pragma unroll
    for (int i = 0; i < 4; ++i)
        #pragma unroll
        for (int jj = 0; jj < 16; ++jj)
            acc[i][jj] = 0.f;
    float mr = -3.0e38f, lr = 0.f;

    const float* ml = (const float*)(sm + 65536);

    asm volatile("s_waitcnt vmcnt(8)" ::: "memory");
    __builtin_amdgcn_s_barrier();

    for (int t = 0; t < 32; ++t) {
        const unsigned char* Kt = sm + (t & 1) * 32768;
        const unsigned char* Vt = Kt + 16384;

        f32x4 mk[2][4];
        #pragma unroll
        for (int kb2 = 0; kb2 < 2; ++kb2)
            #pragma unroll
            for (int rg = 0; rg < 4; ++rg)
                mk[kb2][rg] = *(const f32x4*)(ml + t * 64 + kb2 * 32 + rg * 8 + hi * 4);

        f32x16 sf0, sf1;
        #pragma unroll
        for (int jj = 0; jj < 16; ++jj) { sf0[jj] = 0.f; sf1[jj] = 0.f; }
        __builtin_amdgcn_s_setprio(1);
        #pragma unroll
        for (int ks = 0; ks < 8; ++ks) {
            int row0 = qr, row1 = 32 + qr;
            int s0 = ((2 * ks + hi) ^ (row0 & 7));
            int s1 = ((2 * ks + hi) ^ (row1 & 7));
            bf16x8 kf0 = *(const bf16x8*)(Kt + row0 * 256 + s0 * 16);
            bf16x8 kf1 = *(const bf16x8*)(Kt + row1 * 256 + s1 * 16);
            sf0 = MFMA32(kf0, qf[ks], sf0);
            sf1 = MFMA32(kf1, qf[ks], sf1);
        }
        __builtin_amdgcn_s_setprio(0);

        float sv[2][16];
        #pragma unroll
        for (int reg = 0; reg < 16; ++reg) {
            sv[0][reg] = sf0[reg] * SCL2 + mk[0][reg >> 2][reg & 3];
            sv[1][reg] = sf1[reg] * SCL2 + mk[1][reg >> 2][reg & 3];
        }

        float mx[8];
        #pragma unroll
        for (int jj = 0; jj < 8; ++jj)
            mx[jj] = fmaxf(fmaxf(sv[0][2*jj], sv[0][2*jj+1]),
                           fmaxf(sv[1][2*jj], sv[1][2*jj+1]));
        float m01 = fmaxf(fmaxf(fmaxf(mx[0], mx[1]), fmaxf(mx[2], mx[3])),
                          fmaxf(fmaxf(mx[4], mx[5]), fmaxf(mx[6], mx[7])));
        float2 mp = xswap(m01);
        float mt = fmaxf(mp.x, mp.y);

        float alpha = 1.f;
        int allskip = __all(mt <= mr + 8.f);
        if (!allskip) {
            float nm = fmaxf(mr, mt);
            alpha = __builtin_amdgcn_exp2f(mr - nm);
            mr = nm;
            #pragma unroll
            for (int dblk = 0; dblk < 4; ++dblk)
                #pragma unroll
                for (int reg = 0; reg < 16; ++reg)
                    acc[dblk][reg] *= alpha;
        }

        float s0 = 0.f, s1 = 0.f, s2 = 0.f, s3 = 0.f;
        #pragma unroll
        for (int kb2 = 0; kb2 < 2; ++kb2)
            #pragma unroll
            for (int reg = 0; reg < 16; reg += 4) {
                float p0 = __builtin_amdgcn_exp2f(sv[kb2][reg + 0] - mr);
                float p1 = __builtin_amdgcn_exp2f(sv[kb2][reg + 1] - mr);
                float p2 = __builtin_amdgcn_exp2f(sv[kb2][reg + 2] - mr);
                float p3 = __builtin_amdgcn_exp2f(sv[kb2][reg + 3] - mr);
                sv[kb2][reg + 0] = p0; sv[kb2][reg + 1] = p1;
                sv[kb2][reg + 2] = p2; sv[kb2][reg + 3] = p3;
                s0 += p0; s1 += p1; s2 += p2; s3 += p3;
            }
        float rsl = (s0 + s1) + (s2 + s3);
        float2 rp = xswap(rsl);
        float rs = rp.x + rp.y;
        lr = lr * alpha + rs;

        bf16x8 pfr[4];
        #pragma unroll
        for (int kb16 = 0; kb16 < 4; ++kb16) {
            const int kb2 = kb16 >> 1, i2 = kb16 & 1;
            float* pv = sv[kb2];
            unsigned W00 = packbf(pv[(2*i2+0)*4 + 0], pv[(2*i2+0)*4 + 1]);
            unsigned W01 = packbf(pv[(2*i2+0)*4 + 2], pv[(2*i2+0)*4 + 3]);
            unsigned W10 = packbf(pv[(2*i2+1)*4 + 0], pv[(2*i2+1)*4 + 1]);
            unsigned W11 = packbf(pv[(2*i2+1)*4 + 2], pv[(2*i2+1)*4 + 3]);
            pswap(W00, W10);
            pswap(W01, W11);
            union { unsigned w[4]; bf16x8 v; } u;
            u.w[0] = W00; u.w[1] = W01; u.w[2] = W10; u.w[3] = W11;
            pfr[kb16] = u.v;
        }

        __builtin_amdgcn_s_setprio(1);
        #pragma unroll
        for (int dblk = 0; dblk < 4; ++dblk) {
            int d = dblk * 32 + qr;
            f32x16 a = acc[dblk];
            #pragma unroll
            for (int kb16 = 0; kb16 < 4; ++kb16) {
                int s = ((2 * kb16 + hi) ^ (d & 7));
                bf16x8 vf = *(const bf16x8*)(Vt + d * 128 + s * 16);
                a = MFMA32(vf, pfr[kb16], a);
            }
            acc[dblk] = a;
        }
        __builtin_amdgcn_s_setprio(0);

        __builtin_amdgcn_s_barrier();
        if (t + 2 < 32) {
            STAGE(t + 2, (t & 1) * 32768);
            asm volatile("s_waitcnt vmcnt(8)" ::: "memory");
        } else {
            asm volatile("s_waitcnt vmcnt(0)" ::: "memory");
        }
        __builtin_amdgcn_s_barrier();
    }

    float linv = 1.f / lr;
    unsigned short* orow = O + (rowQ0 + qr) * 2048 + h * 128;
    #pragma unroll
    for (int dblk = 0; dblk < 4; ++dblk)
        #pragma unroll
        for (int rg = 0; rg < 4; ++rg) {
            float v0 = acc[dblk][rg * 4 + 0] * linv;
            float v1 = acc[dblk][rg * 4 + 1] * linv;
            float v2 = acc[dblk][rg * 4 + 2] * linv;
            float v3 = acc[dblk][rg * 4 + 3] * linv;
            uint2 o;
            o.x = packbf(v0, v1);
            o.y = packbf(v2, v3);
            *(uint2*)(orow + dblk * 32 + rg * 8 + hi * 4) = o;
        }
    #undef STAGE
}

// ---------------- host launch ----------------
extern "C" void kernel_launch(void* const* d_in, const int* in_sizes, int n_in,
                              void* d_out, int out_size, void* d_ws, size_t ws_size,
                              hipStream_t stream)
{
    (void)in_sizes; (void)n_in; (void)out_size; (void)ws_size;
    const float* x    = (const float*)d_in[0];
    const float* mask = (const float*)d_in[1];
    const float* Wq   = (const float*)d_in[2];
    const float* bq   = (const float*)d_in[3];
    const float* Wk   = (const float*)d_in[4];
    const float* bk   = (const float*)d_in[5];
    const float* Wv   = (const float*)d_in[6];
    const float* bv   = (const float*)d_in[7];
    const float* Wo   = (const float*)d_in[8];
    const float* bo   = (const float*)d_in[9];
    float* out = (float*)d_out;

    char* ws = (char*)d_ws;
    unsigned short* xb  = (unsigned short*)(ws);
    unsigned short* Wqt = (unsigned short*)(ws + (16u << 20));   // Wqt|Wkt contiguous (QK B)
    unsigned short* Wvt = (unsigned short*)(ws + (32u << 20));
    unsigned short* Wot = (unsigned short*)(ws + (40u << 20));
    unsigned short* Qb  = (unsigned short*)(ws + (48u << 20));
    unsigned short* Kb  = (unsigned short*)(ws + (64u << 20));
    unsigned short* Vtb = (unsigned short*)(ws + (80u << 20));
    unsigned short* Ab  = (unsigned short*)(ws + (16u << 20));   // dead Wqt/Wkt after QK GEMM
    float*          mkl = out;                                   // scratch in d_out until gemmO

    prep_all<<<18436, 256, 0, stream>>>(x, xb, mask, mkl, Wq, Wk, Wv, Wo, Wqt);

    gemmQK<<<256, 512, 0, stream>>>(xb, Wqt, bq, bk, Qb, Kb);
    gemm8_bf16<1><<<256, 512, 0, stream>>>(xb, Wvt, bv, Vtb, MTOT, HHH, HHH);

    attn_fwd<<<512, 256, 0, stream>>>(Qb, Kb, Vtb, mkl, Ab);

    gemm8_bf16<2><<<256, 512, 0, stream>>>(Ab, Wot, bo, out, MTOT, HHH, HHH);
}